// Round 2
// baseline (9267.290 us; speedup 1.0000x reference)
//
#include <hip/hip_runtime.h>

typedef unsigned int u32;
typedef _Float16 half2v __attribute__((ext_vector_type(2)));

#define T_LEN 2048
#define NEG (-10000.0f)

// ---------- helpers ----------
__device__ __forceinline__ float fdot2u(u32 w, u32 h, float acc) {
#if __has_builtin(__builtin_amdgcn_fdot2)
  return __builtin_amdgcn_fdot2(__builtin_bit_cast(half2v, w),
                                __builtin_bit_cast(half2v, h), acc, false);
#else
  half2v a = __builtin_bit_cast(half2v, w);
  half2v b = __builtin_bit_cast(half2v, h);
  return acc + (float)a[0] * (float)b[0] + (float)a[1] * (float)b[1];
#endif
}

__device__ __forceinline__ u32 pack2(float lo, float hi) {
  _Float16 l = (_Float16)lo;  // RN
  _Float16 h = (_Float16)hi;
  unsigned short ul = __builtin_bit_cast(unsigned short, l);
  unsigned short uh = __builtin_bit_cast(unsigned short, h);
  return ((u32)uh << 16) | (u32)ul;
}

// ---------- kernel 1: pack Whh (both dirs) into fp16-pair layout ----------
// reg region : m in [0,92):  b=m>>2, j=m&3 at (d*23+b)*4096 + g*4 + j   (uint4/thread)
// lds region : r=m-92 in [0,36): q=r>>2, j=r&3 at 188416 + d*36864 + q*4096 + g*4 + j
__global__ void pack_whh(const float* __restrict__ Wf, const float* __restrict__ Wb,
                         u32* __restrict__ WP) {
  int idx = blockIdx.x * 256 + threadIdx.x;   // < 262144
  int d   = idx >> 17;
  int rem = idx & 131071;
  int m   = rem >> 10;
  int g   = rem & 1023;
  const float* W = d ? Wb : Wf;
  float2 v = ((const float2*)(W + g * 256))[m];
  u32 p = pack2(v.x, v.y);
  int dest;
  if (m < 92) {
    dest = (d * 23 + (m >> 2)) * 4096 + g * 4 + (m & 3);
  } else {
    int r = m - 92;
    dest = 188416 + d * 36864 + (r >> 2) * 4096 + g * 4 + (r & 3);
  }
  WP[dest] = p;
}

// ---------- kernel 2: embedding gather ----------
__global__ void gather_kernel(const int* __restrict__ words,
                              const float* __restrict__ embed,
                              float* __restrict__ xs) {
  int t = blockIdx.x;
  int k = threadIdx.x;
  xs[t * 256 + k] = embed[(size_t)words[t] * 256 + k];
}

// ---------- kernel 3: XW[d][t][g] = xs[t]·Wih_d[g] + bih[g] + bhh[g] ----------
__global__ __launch_bounds__(256) void gemm_xw(
    const float* __restrict__ xs,
    const float* __restrict__ Wf, const float* __restrict__ Wb,
    const float* __restrict__ bihf, const float* __restrict__ bhhf,
    const float* __restrict__ bihb, const float* __restrict__ bhhb,
    float* __restrict__ XW) {
  __shared__ float lx[32 * 256];
  __shared__ float lw[32 * 132];
  const int tid = threadIdx.x;
  const int t0 = blockIdx.x * 32;
  const int g0 = blockIdx.y * 128;
  const int d  = blockIdx.z;
  const float* W = d ? Wb : Wf;

  #pragma unroll 4
  for (int r = 0; r < 32; ++r) lx[r * 256 + tid] = xs[(t0 + r) * 256 + tid];

  const int tg = tid & 31, tt = tid >> 5;
  float acc[4][4] = {};

  for (int kc = 0; kc < 8; ++kc) {
    __syncthreads();
    #pragma unroll
    for (int r2 = 0; r2 < 16; ++r2) {
      int gg = r2 * 8 + (tid >> 5);
      int k  = tid & 31;
      lw[k * 132 + gg] = W[(g0 + gg) * 256 + kc * 32 + k];
    }
    __syncthreads();
    #pragma unroll
    for (int k = 0; k < 32; ++k) {
      float4 wv = *(const float4*)&lw[k * 132 + tg * 4];
      #pragma unroll
      for (int a = 0; a < 4; ++a) {
        float xa = lx[(tt * 4 + a) * 256 + kc * 32 + k];
        acc[a][0] = fmaf(xa, wv.x, acc[a][0]);
        acc[a][1] = fmaf(xa, wv.y, acc[a][1]);
        acc[a][2] = fmaf(xa, wv.z, acc[a][2]);
        acc[a][3] = fmaf(xa, wv.w, acc[a][3]);
      }
    }
  }
  const float* bih = d ? bihb : bihf;
  const float* bhh = d ? bhhb : bhhf;
  int gcol = g0 + tg * 4;
  float4 bb;
  bb.x = bih[gcol + 0] + bhh[gcol + 0];
  bb.y = bih[gcol + 1] + bhh[gcol + 1];
  bb.z = bih[gcol + 2] + bhh[gcol + 2];
  bb.w = bih[gcol + 3] + bhh[gcol + 3];
  #pragma unroll
  for (int a = 0; a < 4; ++a) {
    float4 o;
    o.x = acc[a][0] + bb.x;
    o.y = acc[a][1] + bb.y;
    o.z = acc[a][2] + bb.z;
    o.w = acc[a][3] + bb.w;
    *(float4*)&XW[((size_t)d * T_LEN + t0 + tt * 4 + a) * 1024 + gcol] = o;
  }
}

// ---------- kernel 4: the sequential bidirectional LSTM ----------
// grid = 2 (d), block = 1024 (g = gate row), dyn LDS 152064 B
// LDS dwords: [0,36864) W-lds [q][g][4], [36864,36992) H2 packed h, [36992,38016) gates
__global__ __launch_bounds__(1024)
__attribute__((amdgpu_waves_per_eu(4, 4)))
void lstm_seq(
    const float* __restrict__ XW, float* __restrict__ HS,
    const u32* __restrict__ wpack,
    const float* __restrict__ h0, const float* __restrict__ c0) {
  extern __shared__ u32 smem[];
  const int g = threadIdx.x;
  const int d = blockIdx.x;

  uint4 wq[23];
  #pragma unroll
  for (int b = 0; b < 23; ++b)
    wq[b] = ((const uint4*)wpack)[(d * 23 + b) * 1024 + g];
  #pragma unroll
  for (int i = 0; i < 36; ++i)
    smem[i * 1024 + g] = wpack[188416 + d * 36864 + i * 1024 + g];

  u32*   H2 = smem + 36864;
  float* GT = (float*)(smem + 36992);

  float c = 0.0f, h = 0.0f;
  if (g < 256) {
    c = c0[d * 256 + g];
    h = h0[d * 256 + g];
    float hp = __shfl_xor(h, 1);
    if (!(g & 1)) H2[g >> 1] = pack2(h, hp);
  }
  __syncthreads();

  const int delta = d ? -1024 : 1024;
  const float* xwp = XW + ((size_t)d * T_LEN + (d ? (T_LEN - 1) : 0)) * 1024 + g;
  float xw_cur = *xwp;

  for (int s = 0; s < T_LEN; ++s) {
    float xw_next = 0.0f;
    if (s < T_LEN - 1) { xwp += delta; xw_next = *xwp; }

    float acc = xw_cur;
    const uint4* H2v = (const uint4*)H2;
    #pragma unroll
    for (int b = 0; b < 23; ++b) {            // h dwords [0,92) from registers
      uint4 hv = H2v[b];
      acc = fdot2u(wq[b].x, hv.x, acc);
      acc = fdot2u(wq[b].y, hv.y, acc);
      acc = fdot2u(wq[b].z, hv.z, acc);
      acc = fdot2u(wq[b].w, hv.w, acc);
    }
    #pragma unroll
    for (int qq = 0; qq < 9; ++qq) {          // h dwords [92,128) from LDS W
      uint4 hv = H2v[23 + qq];
      uint4 wv = *(const uint4*)&smem[qq * 4096 + (g << 2)];
      acc = fdot2u(wv.x, hv.x, acc);
      acc = fdot2u(wv.y, hv.y, acc);
      acc = fdot2u(wv.z, hv.z, acc);
      acc = fdot2u(wv.w, hv.w, acc);
    }
    GT[g] = acc;
    __syncthreads();

    const int t = d ? (T_LEN - 1 - s) : s;
    if (g < 256) {
      float gi = GT[g];
      float gf = GT[256 + g];
      float gc = GT[512 + g];
      float go = GT[768 + g];
      gi = 1.0f / (1.0f + __expf(-gi));
      gf = 1.0f / (1.0f + __expf(-gf));
      go = 1.0f / (1.0f + __expf(-go));
      gc = 1.0f - 2.0f / (__expf(2.0f * gc) + 1.0f);   // tanh
      c = gf * c + gi * gc;
      float th = 1.0f - 2.0f / (__expf(2.0f * c) + 1.0f);
      h = go * th;
      HS[((size_t)d * T_LEN + t) * 256 + g] = h;
      float hp = __shfl_xor(h, 1);
      if (!(g & 1)) H2[g >> 1] = pack2(h, hp);
    }
    __syncthreads();
    xw_cur = xw_next;
  }
}

// ---------- kernel 5: feats[t][n] = [hs_f ; hs_b]·W_out[n] + b_out[n] ----------
__global__ void feats_kernel(const float* __restrict__ hs,
                             const float* __restrict__ wout,
                             const float* __restrict__ bout,
                             float* __restrict__ feats) {
  __shared__ float lf[16 * 257];
  __shared__ float lb[16 * 257];
  const int tid = threadIdx.x;   // 128
  const int t0 = blockIdx.x * 16;
  for (int i = tid; i < 16 * 256; i += 128) {
    int r = i >> 8, k = i & 255;
    lf[r * 257 + k] = hs[(size_t)(t0 + r) * 256 + k];
    lb[r * 257 + k] = hs[(size_t)T_LEN * 256 + (size_t)(t0 + r) * 256 + k];
  }
  __syncthreads();
  const int tl = tid >> 3, n = tid & 7;
  if (n < 7) {
    float acc = bout[n];
    #pragma unroll 8
    for (int k = 0; k < 256; ++k) acc = fmaf(lf[tl * 257 + k], wout[n * 512 + k], acc);
    #pragma unroll 8
    for (int k = 0; k < 256; ++k) acc = fmaf(lb[tl * 257 + k], wout[n * 512 + 256 + k], acc);
    feats[(t0 + tl) * 7 + n] = acc;
  }
}

// ---------- kernel 6: Viterbi decode (1 wave) ----------
__global__ void viterbi_kernel(const float* __restrict__ feats,
                               const float* __restrict__ trans,
                               float* __restrict__ out) {
  __shared__ unsigned char bp[T_LEN][8];
  const int j  = threadIdx.x;          // 64 threads = 1 wave
  const int jc = (j < 7) ? j : 0;
  float Trow[7];
  #pragma unroll
  for (int i = 0; i < 7; ++i) Trow[i] = trans[jc * 7 + i];
  float fv = (j == 5) ? 0.0f : NEG;    // START = 5
  float fcur = feats[jc];
  for (int t = 0; t < T_LEN; ++t) {
    float fnext = (t < T_LEN - 1) ? feats[(t + 1) * 7 + jc] : 0.0f;
    float f0 = __shfl(fv, 0), f1 = __shfl(fv, 1), f2 = __shfl(fv, 2),
          f3 = __shfl(fv, 3), f4 = __shfl(fv, 4), f5 = __shfl(fv, 5),
          f6 = __shfl(fv, 6);
    float best = f0 + Trow[0]; int bi = 0;
    float v;
    v = f1 + Trow[1]; if (v > best) { best = v; bi = 1; }
    v = f2 + Trow[2]; if (v > best) { best = v; bi = 2; }
    v = f3 + Trow[3]; if (v > best) { best = v; bi = 3; }
    v = f4 + Trow[4]; if (v > best) { best = v; bi = 4; }
    v = f5 + Trow[5]; if (v > best) { best = v; bi = 5; }
    v = f6 + Trow[6]; if (v > best) { best = v; bi = 6; }
    if (j < 7) {
      bp[t][j] = (unsigned char)bi;
      fv = best + fcur;
    }
    fcur = fnext;
  }
  float term = fv + trans[42 + jc];    // transitions[END=6][j]
  float best = __shfl(term, 0); int bt = 0;
  #pragma unroll
  for (int i = 1; i < 7; ++i) {
    float ti = __shfl(term, i);
    if (ti > best) { best = ti; bt = i; }
  }
  __syncthreads();
  if (j == 0) {
    out[0] = best;
    int tag = bt;
    for (int t = T_LEN - 1; t >= 0; --t) {
      out[1 + t] = (float)tag;
      tag = bp[t][tag];
    }
  }
}

// ---------- host ----------
extern "C" void kernel_launch(void* const* d_in, const int* in_sizes, int n_in,
                              void* d_out, int out_size, void* d_ws, size_t ws_size,
                              hipStream_t stream) {
  const int*   words = (const int*)d_in[0];
  const float* embed = (const float*)d_in[1];
  const float* Wih_f = (const float*)d_in[2];
  const float* Whh_f = (const float*)d_in[3];
  const float* bih_f = (const float*)d_in[4];
  const float* bhh_f = (const float*)d_in[5];
  const float* Wih_b = (const float*)d_in[6];
  const float* Whh_b = (const float*)d_in[7];
  const float* bih_b = (const float*)d_in[8];
  const float* bhh_b = (const float*)d_in[9];
  const float* Wout  = (const float*)d_in[10];
  const float* bout  = (const float*)d_in[11];
  const float* trans = (const float*)d_in[12];
  const float* h0    = (const float*)d_in[13];
  const float* c0    = (const float*)d_in[14];

  float* ws = (float*)d_ws;
  float* XW = ws;                        // 2*2048*1024           = 4,194,304 f
  float* HS = ws + 4194304;              // 2*2048*256            = 1,048,576 f
  float* XS = ws + 5242880;              // 2048*256              =   524,288 f
  float* FE = ws + 5767168;              // 2048*7                =    14,336 f
  u32*   WP = (u32*)(ws + 5781504);      // 262,144 dwords

  pack_whh<<<1024, 256, 0, stream>>>(Whh_f, Whh_b, WP);
  gather_kernel<<<T_LEN, 256, 0, stream>>>(words, embed, XS);
  dim3 ggrid(T_LEN / 32, 1024 / 128, 2);
  gemm_xw<<<ggrid, 256, 0, stream>>>(XS, Wih_f, Wih_b, bih_f, bhh_f, bih_b, bhh_b, XW);
  lstm_seq<<<2, 1024, 152064, stream>>>(XW, HS, WP, h0, c0);
  feats_kernel<<<128, 128, 0, stream>>>(HS, Wout, bout, FE);
  viterbi_kernel<<<1, 64, 0, stream>>>(FE, trans, (float*)d_out);
}

// Round 3
// 4217.337 us; speedup vs baseline: 2.1974x; 2.1974x over previous
//
#include <hip/hip_runtime.h>

typedef unsigned int u32;
typedef _Float16 half2v __attribute__((ext_vector_type(2)));

#define T_LEN 2048
#define NEG (-10000.0f)

// lstm_seq geometry
#define RQ 24            // register quads per row (96 dwords)
#define LDW 32           // LDS weight dwords per row
#define WROW 33          // padded LDS row stride (dwords): bank = (r+i)%32, conflict-free
#define REG_TOT 196608   // 2 dirs * 24 quads * 1024 rows * 4 dwords
#define SM_H2 33792      // 1024*33 dwords of W
#define SM_GT 33920      // H2 + 128
#define SM_TOT 34944     // GT + 1024
// dynamic LDS bytes = 34944*4 = 139776

// ---------- helpers ----------
__device__ __forceinline__ float fdot2u(u32 w, u32 h, float acc) {
#if __has_builtin(__builtin_amdgcn_fdot2)
  return __builtin_amdgcn_fdot2(__builtin_bit_cast(half2v, w),
                                __builtin_bit_cast(half2v, h), acc, false);
#else
  half2v a = __builtin_bit_cast(half2v, w);
  half2v b = __builtin_bit_cast(half2v, h);
  return acc + (float)a[0] * (float)b[0] + (float)a[1] * (float)b[1];
#endif
}

__device__ __forceinline__ u32 pack2(float lo, float hi) {
  _Float16 l = (_Float16)lo;  // RN
  _Float16 h = (_Float16)hi;
  unsigned short ul = __builtin_bit_cast(unsigned short, l);
  unsigned short uh = __builtin_bit_cast(unsigned short, h);
  return ((u32)uh << 16) | (u32)ul;
}

// ---------- kernel 1: pack Whh (both dirs) into fp16-pair layout ----------
// reg region : m in [0,96):  q=m>>2, j=m&3  at ((d*24+q)*1024 + g)*4 + j   (uint4/lane)
// lds region : i=m-96 in [0,32)            at REG_TOT + d*32768 + i*1024 + g
__global__ void pack_whh(const float* __restrict__ Wf, const float* __restrict__ Wb,
                         u32* __restrict__ WP) {
  int idx = blockIdx.x * 256 + threadIdx.x;   // < 262144
  int d   = idx >> 17;
  int rem = idx & 131071;
  int m   = rem >> 10;
  int g   = rem & 1023;
  const float* W = d ? Wb : Wf;
  float2 v = ((const float2*)(W + g * 256))[m];
  u32 p = pack2(v.x, v.y);
  int dest;
  if (m < 96) {
    dest = ((d * 24 + (m >> 2)) * 1024 + g) * 4 + (m & 3);
  } else {
    dest = REG_TOT + d * 32768 + (m - 96) * 1024 + g;
  }
  WP[dest] = p;
}

// ---------- kernel 2: embedding gather ----------
__global__ void gather_kernel(const int* __restrict__ words,
                              const float* __restrict__ embed,
                              float* __restrict__ xs) {
  int t = blockIdx.x;
  int k = threadIdx.x;
  xs[t * 256 + k] = embed[(size_t)words[t] * 256 + k];
}

// ---------- kernel 3: XW[d][t][g] = xs[t]·Wih_d[g] + bih[g] + bhh[g] ----------
__global__ __launch_bounds__(256) void gemm_xw(
    const float* __restrict__ xs,
    const float* __restrict__ Wf, const float* __restrict__ Wb,
    const float* __restrict__ bihf, const float* __restrict__ bhhf,
    const float* __restrict__ bihb, const float* __restrict__ bhhb,
    float* __restrict__ XW) {
  __shared__ float lx[32 * 256];
  __shared__ float lw[32 * 132];
  const int tid = threadIdx.x;
  const int t0 = blockIdx.x * 32;
  const int g0 = blockIdx.y * 128;
  const int d  = blockIdx.z;
  const float* W = d ? Wb : Wf;

  #pragma unroll 4
  for (int r = 0; r < 32; ++r) lx[r * 256 + tid] = xs[(t0 + r) * 256 + tid];

  const int tg = tid & 31, tt = tid >> 5;
  float acc[4][4] = {};

  for (int kc = 0; kc < 8; ++kc) {
    __syncthreads();
    #pragma unroll
    for (int r2 = 0; r2 < 16; ++r2) {
      int gg = r2 * 8 + (tid >> 5);
      int k  = tid & 31;
      lw[k * 132 + gg] = W[(g0 + gg) * 256 + kc * 32 + k];
    }
    __syncthreads();
    #pragma unroll
    for (int k = 0; k < 32; ++k) {
      float4 wv = *(const float4*)&lw[k * 132 + tg * 4];
      #pragma unroll
      for (int a = 0; a < 4; ++a) {
        float xa = lx[(tt * 4 + a) * 256 + kc * 32 + k];
        acc[a][0] = fmaf(xa, wv.x, acc[a][0]);
        acc[a][1] = fmaf(xa, wv.y, acc[a][1]);
        acc[a][2] = fmaf(xa, wv.z, acc[a][2]);
        acc[a][3] = fmaf(xa, wv.w, acc[a][3]);
      }
    }
  }
  const float* bih = d ? bihb : bihf;
  const float* bhh = d ? bhhb : bhhf;
  int gcol = g0 + tg * 4;
  float4 bb;
  bb.x = bih[gcol + 0] + bhh[gcol + 0];
  bb.y = bih[gcol + 1] + bhh[gcol + 1];
  bb.z = bih[gcol + 2] + bhh[gcol + 2];
  bb.w = bih[gcol + 3] + bhh[gcol + 3];
  #pragma unroll
  for (int a = 0; a < 4; ++a) {
    float4 o;
    o.x = acc[a][0] + bb.x;
    o.y = acc[a][1] + bb.y;
    o.z = acc[a][2] + bb.z;
    o.w = acc[a][3] + bb.w;
    *(float4*)&XW[((size_t)d * T_LEN + t0 + tt * 4 + a) * 1024 + gcol] = o;
  }
}

// ---------- kernel 4: the sequential bidirectional LSTM ----------
// grid = 2 (d = direction), block = 512; thread owns rows tid and tid+512.
// 96 weight dwords/row in VGPRs, 32 in LDS ([row][33] padded, conflict-free).
__global__ void __launch_bounds__(512)
__attribute__((amdgpu_waves_per_eu(2, 2), amdgpu_num_vgpr(248)))
lstm_seq(
    const float* __restrict__ XW, float* __restrict__ HS,
    const u32* __restrict__ wpack,
    const float* __restrict__ h0, const float* __restrict__ c0) {
  extern __shared__ u32 smem[];
  const int tid = threadIdx.x;
  const int d = blockIdx.x;
  const int r0 = tid, r1 = tid + 512;

  uint4 wa[RQ], wb[RQ];
  const uint4* wr = (const uint4*)wpack;
  #pragma unroll
  for (int q = 0; q < RQ; ++q) {
    wa[q] = wr[(d * RQ + q) * 1024 + r0];
    wb[q] = wr[(d * RQ + q) * 1024 + r1];
  }
  {
    const u32* wl = wpack + REG_TOT + d * 32768;
    #pragma unroll
    for (int i = 0; i < LDW; ++i) {
      smem[r0 * WROW + i] = wl[i * 1024 + r0];
      smem[r1 * WROW + i] = wl[i * 1024 + r1];
    }
  }

  u32*   H2 = smem + SM_H2;
  float* GT = (float*)(smem + SM_GT);

  float c = 0.0f, h = 0.0f;
  if (tid < 256) {
    c = c0[d * 256 + tid];
    h = h0[d * 256 + tid];
    float hp = __shfl_xor(h, 1);
    if (!(tid & 1)) H2[tid >> 1] = pack2(h, hp);
  }
  __syncthreads();

  const int delta = d ? -1024 : 1024;
  const float* xwp = XW + ((size_t)d * T_LEN + (d ? (T_LEN - 1) : 0)) * 1024 + tid;
  float xw0c = xwp[0], xw1c = xwp[512];

  for (int s = 0; s < T_LEN; ++s) {
    float xw0n = 0.0f, xw1n = 0.0f;
    if (s < T_LEN - 1) { xwp += delta; xw0n = xwp[0]; xw1n = xwp[512]; }

    const uint4* H2v = (const uint4*)H2;
    float a0 = xw0c, b0 = 0.0f;   // two chains for row r0
    float a1 = xw1c, b1 = 0.0f;   // two chains for row r1
    #pragma unroll
    for (int q = 0; q < RQ; ++q) {          // h dwords [0,96) : reg weights
      uint4 hv = H2v[q];
      a0 = fdot2u(wa[q].x, hv.x, a0);
      a1 = fdot2u(wb[q].x, hv.x, a1);
      b0 = fdot2u(wa[q].y, hv.y, b0);
      b1 = fdot2u(wb[q].y, hv.y, b1);
      a0 = fdot2u(wa[q].z, hv.z, a0);
      a1 = fdot2u(wb[q].z, hv.z, a1);
      b0 = fdot2u(wa[q].w, hv.w, b0);
      b1 = fdot2u(wb[q].w, hv.w, b1);
    }
    #pragma unroll
    for (int q = 0; q < 8; ++q) {           // h dwords [96,128) : LDS weights
      uint4 hv = H2v[RQ + q];
      int i0 = q * 4;
      u32 wA0 = smem[r0 * WROW + i0 + 0], wA1 = smem[r0 * WROW + i0 + 1];
      u32 wA2 = smem[r0 * WROW + i0 + 2], wA3 = smem[r0 * WROW + i0 + 3];
      u32 wB0 = smem[r1 * WROW + i0 + 0], wB1 = smem[r1 * WROW + i0 + 1];
      u32 wB2 = smem[r1 * WROW + i0 + 2], wB3 = smem[r1 * WROW + i0 + 3];
      a0 = fdot2u(wA0, hv.x, a0);
      a1 = fdot2u(wB0, hv.x, a1);
      b0 = fdot2u(wA1, hv.y, b0);
      b1 = fdot2u(wB1, hv.y, b1);
      a0 = fdot2u(wA2, hv.z, a0);
      a1 = fdot2u(wB2, hv.z, a1);
      b0 = fdot2u(wA3, hv.w, b0);
      b1 = fdot2u(wB3, hv.w, b1);
    }
    GT[r0] = a0 + b0;
    GT[r1] = a1 + b1;
    __syncthreads();

    const int t = d ? (T_LEN - 1 - s) : s;
    if (tid < 256) {
      float gi = GT[tid];
      float gf = GT[256 + tid];
      float gc = GT[512 + tid];
      float go = GT[768 + tid];
      gi = 1.0f / (1.0f + __expf(-gi));
      gf = 1.0f / (1.0f + __expf(-gf));
      go = 1.0f / (1.0f + __expf(-go));
      gc = 1.0f - 2.0f / (__expf(2.0f * gc) + 1.0f);   // tanh
      c = gf * c + gi * gc;
      float th = 1.0f - 2.0f / (__expf(2.0f * c) + 1.0f);
      h = go * th;
      HS[((size_t)d * T_LEN + t) * 256 + tid] = h;
      float hp = __shfl_xor(h, 1);
      if (!(tid & 1)) H2[tid >> 1] = pack2(h, hp);
    }
    __syncthreads();
    xw0c = xw0n;
    xw1c = xw1n;
  }
}

// ---------- kernel 5: feats[t][n] = [hs_f ; hs_b]·W_out[n] + b_out[n] ----------
__global__ void feats_kernel(const float* __restrict__ hs,
                             const float* __restrict__ wout,
                             const float* __restrict__ bout,
                             float* __restrict__ feats) {
  __shared__ float lf[16 * 257];
  __shared__ float lb[16 * 257];
  const int tid = threadIdx.x;   // 128
  const int t0 = blockIdx.x * 16;
  for (int i = tid; i < 16 * 256; i += 128) {
    int r = i >> 8, k = i & 255;
    lf[r * 257 + k] = hs[(size_t)(t0 + r) * 256 + k];
    lb[r * 257 + k] = hs[(size_t)T_LEN * 256 + (size_t)(t0 + r) * 256 + k];
  }
  __syncthreads();
  const int tl = tid >> 3, n = tid & 7;
  if (n < 7) {
    float acc = bout[n];
    #pragma unroll 8
    for (int k = 0; k < 256; ++k) acc = fmaf(lf[tl * 257 + k], wout[n * 512 + k], acc);
    #pragma unroll 8
    for (int k = 0; k < 256; ++k) acc = fmaf(lb[tl * 257 + k], wout[n * 512 + 256 + k], acc);
    feats[(t0 + tl) * 7 + n] = acc;
  }
}

// ---------- kernel 6: Viterbi decode (1 wave) ----------
__global__ void viterbi_kernel(const float* __restrict__ feats,
                               const float* __restrict__ trans,
                               float* __restrict__ out) {
  __shared__ unsigned char bp[T_LEN][8];
  const int j  = threadIdx.x;          // 64 threads = 1 wave
  const int jc = (j < 7) ? j : 0;
  float Trow[7];
  #pragma unroll
  for (int i = 0; i < 7; ++i) Trow[i] = trans[jc * 7 + i];
  float fv = (j == 5) ? 0.0f : NEG;    // START = 5
  float fcur = feats[jc];
  for (int t = 0; t < T_LEN; ++t) {
    float fnext = (t < T_LEN - 1) ? feats[(t + 1) * 7 + jc] : 0.0f;
    float f0 = __shfl(fv, 0), f1 = __shfl(fv, 1), f2 = __shfl(fv, 2),
          f3 = __shfl(fv, 3), f4 = __shfl(fv, 4), f5 = __shfl(fv, 5),
          f6 = __shfl(fv, 6);
    float best = f0 + Trow[0]; int bi = 0;
    float v;
    v = f1 + Trow[1]; if (v > best) { best = v; bi = 1; }
    v = f2 + Trow[2]; if (v > best) { best = v; bi = 2; }
    v = f3 + Trow[3]; if (v > best) { best = v; bi = 3; }
    v = f4 + Trow[4]; if (v > best) { best = v; bi = 4; }
    v = f5 + Trow[5]; if (v > best) { best = v; bi = 5; }
    v = f6 + Trow[6]; if (v > best) { best = v; bi = 6; }
    if (j < 7) {
      bp[t][j] = (unsigned char)bi;
      fv = best + fcur;
    }
    fcur = fnext;
  }
  float term = fv + trans[42 + jc];    // transitions[END=6][j]
  float best = __shfl(term, 0); int bt = 0;
  #pragma unroll
  for (int i = 1; i < 7; ++i) {
    float ti = __shfl(term, i);
    if (ti > best) { best = ti; bt = i; }
  }
  __syncthreads();
  if (j == 0) {
    out[0] = best;
    int tag = bt;
    for (int t = T_LEN - 1; t >= 0; --t) {
      out[1 + t] = (float)tag;
      tag = bp[t][tag];
    }
  }
}

// ---------- host ----------
extern "C" void kernel_launch(void* const* d_in, const int* in_sizes, int n_in,
                              void* d_out, int out_size, void* d_ws, size_t ws_size,
                              hipStream_t stream) {
  const int*   words = (const int*)d_in[0];
  const float* embed = (const float*)d_in[1];
  const float* Wih_f = (const float*)d_in[2];
  const float* Whh_f = (const float*)d_in[3];
  const float* bih_f = (const float*)d_in[4];
  const float* bhh_f = (const float*)d_in[5];
  const float* Wih_b = (const float*)d_in[6];
  const float* Whh_b = (const float*)d_in[7];
  const float* bih_b = (const float*)d_in[8];
  const float* bhh_b = (const float*)d_in[9];
  const float* Wout  = (const float*)d_in[10];
  const float* bout  = (const float*)d_in[11];
  const float* trans = (const float*)d_in[12];
  const float* h0    = (const float*)d_in[13];
  const float* c0    = (const float*)d_in[14];

  float* ws = (float*)d_ws;
  float* XW = ws;                        // 2*2048*1024           = 4,194,304 f
  float* HS = ws + 4194304;              // 2*2048*256            = 1,048,576 f
  float* XS = ws + 5242880;              // 2048*256              =   524,288 f
  float* FE = ws + 5767168;              // 2048*7                =    14,336 f
  u32*   WP = (u32*)(ws + 5781504);      // 262,144 dwords

  pack_whh<<<1024, 256, 0, stream>>>(Whh_f, Whh_b, WP);
  gather_kernel<<<T_LEN, 256, 0, stream>>>(words, embed, XS);
  dim3 ggrid(T_LEN / 32, 1024 / 128, 2);
  gemm_xw<<<ggrid, 256, 0, stream>>>(XS, Wih_f, Wih_b, bih_f, bhh_f, bih_b, bhh_b, XW);
  lstm_seq<<<2, 512, SM_TOT * 4, stream>>>(XW, HS, WP, h0, c0);
  feats_kernel<<<128, 128, 0, stream>>>(HS, Wout, bout, FE);
  viterbi_kernel<<<1, 64, 0, stream>>>(FE, trans, (float*)d_out);
}

// Round 4
// 4159.455 us; speedup vs baseline: 2.2280x; 1.0139x over previous
//
#include <hip/hip_runtime.h>

typedef unsigned int u32;
typedef _Float16 half2v __attribute__((ext_vector_type(2)));

#define T_LEN 2048
#define NEG (-10000.0f)

// lstm_seq geometry
#define RQ 24            // 24 quads = 96 weight dwords per row in VGPRs
#define LQ 8             // 8 quads  = 32 weight dwords per row in LDS (XOR-swizzled)
#define REG_TOT 196608   // 2 dirs * 24 quads * 1024 rows * 4 dwords
#define SM_H2 32768      // after 1024 rows * 32 dwords of LDS weights
#define SM_GT 32896      // H2 + 128
#define SM_TOT 33920     // GT + 1024  -> 135680 bytes dynamic LDS

// ---------- helpers ----------
__device__ __forceinline__ float fdot2u(u32 w, u32 h, float acc) {
#if __has_builtin(__builtin_amdgcn_fdot2)
  return __builtin_amdgcn_fdot2(__builtin_bit_cast(half2v, w),
                                __builtin_bit_cast(half2v, h), acc, false);
#else
  half2v a = __builtin_bit_cast(half2v, w);
  half2v b = __builtin_bit_cast(half2v, h);
  return acc + (float)a[0] * (float)b[0] + (float)a[1] * (float)b[1];
#endif
}

__device__ __forceinline__ u32 rdlane_u32(u32 v, int lane) {
#if __has_builtin(__builtin_amdgcn_readlane)
  return (u32)__builtin_amdgcn_readlane((int)v, lane);
#else
  return (u32)__shfl((int)v, lane);
#endif
}

__device__ __forceinline__ float rdlane_f32(float v, int lane) {
  return __builtin_bit_cast(float, rdlane_u32(__builtin_bit_cast(u32, v), lane));
}

__device__ __forceinline__ u32 pack2(float lo, float hi) {
  _Float16 l = (_Float16)lo;  // RN
  _Float16 h = (_Float16)hi;
  unsigned short ul = __builtin_bit_cast(unsigned short, l);
  unsigned short uh = __builtin_bit_cast(unsigned short, h);
  return ((u32)uh << 16) | (u32)ul;
}

// ---------- kernel 1: pack Whh (both dirs) into fp16-pair layout ----------
// m = h2-dword index [0,128) of row g.
// reg region : m in [0,96):  dword ((d*24 + m>>2)*1024 + g)*4 + (m&3)
// lds region : mm=m-96 in [0,32): REG_TOT + d*32768 + g*32 + 4*((mm>>2)^(g&7)) + (mm&3)
__global__ void pack_whh(const float* __restrict__ Wf, const float* __restrict__ Wb,
                         u32* __restrict__ WP) {
  int idx = blockIdx.x * 256 + threadIdx.x;   // < 262144
  int d   = idx >> 17;
  int rem = idx & 131071;
  int m   = rem >> 10;
  int g   = rem & 1023;
  const float* W = d ? Wb : Wf;
  float2 v = ((const float2*)(W + g * 256))[m];
  u32 p = pack2(v.x, v.y);
  int dest;
  if (m < 96) {
    dest = ((d * 24 + (m >> 2)) * 1024 + g) * 4 + (m & 3);
  } else {
    int mm = m - 96;
    dest = REG_TOT + d * 32768 + g * 32 + 4 * ((mm >> 2) ^ (g & 7)) + (mm & 3);
  }
  WP[dest] = p;
}

// ---------- kernel 2: embedding gather ----------
__global__ void gather_kernel(const int* __restrict__ words,
                              const float* __restrict__ embed,
                              float* __restrict__ xs) {
  int t = blockIdx.x;
  int k = threadIdx.x;
  xs[t * 256 + k] = embed[(size_t)words[t] * 256 + k];
}

// ---------- kernel 3: XW[d][t][g] = xs[t]·Wih_d[g] + bih[g] + bhh[g] ----------
__global__ __launch_bounds__(256) void gemm_xw(
    const float* __restrict__ xs,
    const float* __restrict__ Wf, const float* __restrict__ Wb,
    const float* __restrict__ bihf, const float* __restrict__ bhhf,
    const float* __restrict__ bihb, const float* __restrict__ bhhb,
    float* __restrict__ XW) {
  __shared__ float lx[32 * 256];
  __shared__ float lw[32 * 132];
  const int tid = threadIdx.x;
  const int t0 = blockIdx.x * 32;
  const int g0 = blockIdx.y * 128;
  const int d  = blockIdx.z;
  const float* W = d ? Wb : Wf;

  #pragma unroll 4
  for (int r = 0; r < 32; ++r) lx[r * 256 + tid] = xs[(t0 + r) * 256 + tid];

  const int tg = tid & 31, tt = tid >> 5;
  float acc[4][4] = {};

  for (int kc = 0; kc < 8; ++kc) {
    __syncthreads();
    #pragma unroll
    for (int r2 = 0; r2 < 16; ++r2) {
      int gg = r2 * 8 + (tid >> 5);
      int k  = tid & 31;
      lw[k * 132 + gg] = W[(g0 + gg) * 256 + kc * 32 + k];
    }
    __syncthreads();
    #pragma unroll
    for (int k = 0; k < 32; ++k) {
      float4 wv = *(const float4*)&lw[k * 132 + tg * 4];
      #pragma unroll
      for (int a = 0; a < 4; ++a) {
        float xa = lx[(tt * 4 + a) * 256 + kc * 32 + k];
        acc[a][0] = fmaf(xa, wv.x, acc[a][0]);
        acc[a][1] = fmaf(xa, wv.y, acc[a][1]);
        acc[a][2] = fmaf(xa, wv.z, acc[a][2]);
        acc[a][3] = fmaf(xa, wv.w, acc[a][3]);
      }
    }
  }
  const float* bih = d ? bihb : bihf;
  const float* bhh = d ? bhhb : bhhf;
  int gcol = g0 + tg * 4;
  float4 bb;
  bb.x = bih[gcol + 0] + bhh[gcol + 0];
  bb.y = bih[gcol + 1] + bhh[gcol + 1];
  bb.z = bih[gcol + 2] + bhh[gcol + 2];
  bb.w = bih[gcol + 3] + bhh[gcol + 3];
  #pragma unroll
  for (int a = 0; a < 4; ++a) {
    float4 o;
    o.x = acc[a][0] + bb.x;
    o.y = acc[a][1] + bb.y;
    o.z = acc[a][2] + bb.z;
    o.w = acc[a][3] + bb.w;
    *(float4*)&XW[((size_t)d * T_LEN + t0 + tt * 4 + a) * 1024 + gcol] = o;
  }
}

// ---------- kernel 4: the sequential bidirectional LSTM ----------
// grid = 2 (d), block = 512; thread owns rows tid and tid+512.
// 96 weight dwords/row in VGPRs; 32 in LDS (b128, XOR-quad swizzle).
// h broadcast via v_readlane (VALU) from per-wave lane-resident copy.
__global__ void __launch_bounds__(512)
__attribute__((amdgpu_waves_per_eu(2, 2)))
lstm_seq(
    const float* __restrict__ XW, float* __restrict__ HS,
    const u32* __restrict__ wpack,
    const float* __restrict__ h0, const float* __restrict__ c0) {
  extern __shared__ u32 smem[];
  const int tid = threadIdx.x;
  const int d = blockIdx.x;
  const int r0 = tid, r1 = tid + 512;
  const int lane = tid & 63;
  const int sw = tid & 7;                 // == r0&7 == r1&7 (512 % 8 == 0)

  uint4 wa[RQ], wb[RQ];
  const uint4* wr = (const uint4*)wpack;
  #pragma unroll
  for (int q = 0; q < RQ; ++q) {
    wa[q] = wr[(d * RQ + q) * 1024 + r0];
    wb[q] = wr[(d * RQ + q) * 1024 + r1];
  }
  {
    const u32* wl = wpack + REG_TOT + d * 32768;
    #pragma unroll
    for (int i = 0; i < 64; ++i)          // swizzle baked into global layout
      smem[tid + i * 512] = wl[tid + i * 512];
  }

  u32*   H2 = smem + SM_H2;
  float* GT = (float*)(smem + SM_GT);
  const u32* wl0 = &smem[r0 * 32];
  const u32* wl1 = &smem[r1 * 32];

  float c = 0.0f, h = 0.0f;
  if (tid < 256) {
    c = c0[d * 256 + tid];
    h = h0[d * 256 + tid];
    float hp = __shfl_xor(h, 1);
    if (!(tid & 1)) H2[tid >> 1] = pack2(h, hp);
  }
  __syncthreads();

  u32 hA = H2[lane];          // h2 dwords [0,64)
  u32 hB = H2[64 + lane];     // h2 dwords [64,128)

  const int delta = d ? -1024 : 1024;
  const float* xwp = XW + ((size_t)d * T_LEN + (d ? (T_LEN - 1) : 0)) * 1024 + tid;
  float xw0c = xwp[0], xw1c = xwp[512];

  for (int s = 0; s < T_LEN; ++s) {
    float xw0n = 0.0f, xw1n = 0.0f;
    if (s < T_LEN - 1) { xwp += delta; xw0n = xwp[0]; xw1n = xwp[512]; }

    float a0 = xw0c, b0 = 0.0f;   // two acc chains for row r0
    float a1 = xw1c, b1 = 0.0f;   // two acc chains for row r1
    #pragma unroll
    for (int q = 0; q < RQ; ++q) {        // h2 dwords [0,96) : reg weights
      const int i0 = 4 * q;
      u32 h0v, h1v, h2v, h3v;
      if (i0 < 64) {
        h0v = rdlane_u32(hA, i0 + 0);
        h1v = rdlane_u32(hA, i0 + 1);
        h2v = rdlane_u32(hA, i0 + 2);
        h3v = rdlane_u32(hA, i0 + 3);
      } else {
        h0v = rdlane_u32(hB, i0 - 64 + 0);
        h1v = rdlane_u32(hB, i0 - 64 + 1);
        h2v = rdlane_u32(hB, i0 - 64 + 2);
        h3v = rdlane_u32(hB, i0 - 64 + 3);
      }
      a0 = fdot2u(wa[q].x, h0v, a0);
      a1 = fdot2u(wb[q].x, h0v, a1);
      b0 = fdot2u(wa[q].y, h1v, b0);
      b1 = fdot2u(wb[q].y, h1v, b1);
      a0 = fdot2u(wa[q].z, h2v, a0);
      a1 = fdot2u(wb[q].z, h2v, a1);
      b0 = fdot2u(wa[q].w, h3v, b0);
      b1 = fdot2u(wb[q].w, h3v, b1);
    }
    #pragma unroll
    for (int q = 0; q < LQ; ++q) {        // h2 dwords [96,128) : LDS weights
      const int ln = 32 + 4 * q;
      uint4 wA = *(const uint4*)&wl0[4 * (q ^ sw)];
      uint4 wB = *(const uint4*)&wl1[4 * (q ^ sw)];
      u32 h0v = rdlane_u32(hB, ln + 0);
      u32 h1v = rdlane_u32(hB, ln + 1);
      u32 h2v = rdlane_u32(hB, ln + 2);
      u32 h3v = rdlane_u32(hB, ln + 3);
      a0 = fdot2u(wA.x, h0v, a0);
      a1 = fdot2u(wB.x, h0v, a1);
      b0 = fdot2u(wA.y, h1v, b0);
      b1 = fdot2u(wB.y, h1v, b1);
      a0 = fdot2u(wA.z, h2v, a0);
      a1 = fdot2u(wB.z, h2v, a1);
      b0 = fdot2u(wA.w, h3v, b0);
      b1 = fdot2u(wB.w, h3v, b1);
    }
    GT[r0] = a0 + b0;
    GT[r1] = a1 + b1;
    __syncthreads();

    const int t = d ? (T_LEN - 1 - s) : s;
    if (tid < 256) {
      float gi = GT[tid];
      float gf = GT[256 + tid];
      float gc = GT[512 + tid];
      float go = GT[768 + tid];
      gi = 1.0f / (1.0f + __expf(-gi));
      gf = 1.0f / (1.0f + __expf(-gf));
      go = 1.0f / (1.0f + __expf(-go));
      gc = 1.0f - 2.0f / (__expf(2.0f * gc) + 1.0f);   // tanh
      c = gf * c + gi * gc;
      float th = 1.0f - 2.0f / (__expf(2.0f * c) + 1.0f);
      h = go * th;
      HS[((size_t)d * T_LEN + t) * 256 + tid] = h;
      float hp = __shfl_xor(h, 1);
      if (!(tid & 1)) H2[tid >> 1] = pack2(h, hp);
    }
    __syncthreads();
    hA = H2[lane];
    hB = H2[64 + lane];
    xw0c = xw0n;
    xw1c = xw1n;
  }
}

// ---------- kernel 5: feats[t][n] = [hs_f ; hs_b]·W_out[n] + b_out[n] ----------
__global__ void feats_kernel(const float* __restrict__ hs,
                             const float* __restrict__ wout,
                             const float* __restrict__ bout,
                             float* __restrict__ feats) {
  __shared__ float lf[16 * 257];
  __shared__ float lb[16 * 257];
  const int tid = threadIdx.x;   // 128
  const int t0 = blockIdx.x * 16;
  for (int i = tid; i < 16 * 256; i += 128) {
    int r = i >> 8, k = i & 255;
    lf[r * 257 + k] = hs[(size_t)(t0 + r) * 256 + k];
    lb[r * 257 + k] = hs[(size_t)T_LEN * 256 + (size_t)(t0 + r) * 256 + k];
  }
  __syncthreads();
  const int tl = tid >> 3, n = tid & 7;
  if (n < 7) {
    float acc = bout[n];
    #pragma unroll 8
    for (int k = 0; k < 256; ++k) acc = fmaf(lf[tl * 257 + k], wout[n * 512 + k], acc);
    #pragma unroll 8
    for (int k = 0; k < 256; ++k) acc = fmaf(lb[tl * 257 + k], wout[n * 512 + 256 + k], acc);
    feats[(t0 + tl) * 7 + n] = acc;
  }
}

// ---------- kernel 6: Viterbi decode ----------
// 1 block, 256 threads. feats in LDS; forward on wave 0 via readlane;
// blocked backtrack: 32 segment maps (parallel) + boundary chain + rewalk.
// Dyn LDS bytes: fe 57344 | bp 16384 | G 256 | bt 64  => 74048
__global__ __launch_bounds__(256) void viterbi_kernel(
    const float* __restrict__ feats,
    const float* __restrict__ trans,
    float* __restrict__ out) {
  extern __shared__ char vsm[];
  float*         fe = (float*)vsm;                       // [T_LEN*7]
  unsigned char* bp = (unsigned char*)(vsm + 57344);     // [T_LEN][8]
  unsigned char* G  = (unsigned char*)(vsm + 73728);     // [32][8]
  unsigned char* bt = (unsigned char*)(vsm + 73984);     // [32]
  const int tid = threadIdx.x;

  for (int i = tid; i < T_LEN * 7; i += 256) fe[i] = feats[i];
  __syncthreads();

  if (tid < 64) {
    const int j  = tid;
    const int jc = (j < 7) ? j : 0;
    float Trow[7];
    #pragma unroll
    for (int i = 0; i < 7; ++i) Trow[i] = trans[jc * 7 + i];
    float fv = (j == 5) ? 0.0f : NEG;    // START = 5
    for (int t = 0; t < T_LEN; ++t) {
      float f0 = rdlane_f32(fv, 0), f1 = rdlane_f32(fv, 1), f2 = rdlane_f32(fv, 2),
            f3 = rdlane_f32(fv, 3), f4 = rdlane_f32(fv, 4), f5 = rdlane_f32(fv, 5),
            f6 = rdlane_f32(fv, 6);
      float v0 = f0 + Trow[0], v1 = f1 + Trow[1], v2 = f2 + Trow[2],
            v3 = f3 + Trow[3], v4 = f4 + Trow[4], v5 = f5 + Trow[5],
            v6 = f6 + Trow[6];
      // first-max argmax tree (lower index wins ties), matches jnp.argmax
      bool c01 = v0 >= v1;  float m01 = c01 ? v0 : v1;  int i01 = c01 ? 0 : 1;
      bool c23 = v2 >= v3;  float m23 = c23 ? v2 : v3;  int i23 = c23 ? 2 : 3;
      bool c45 = v4 >= v5;  float m45 = c45 ? v4 : v5;  int i45 = c45 ? 4 : 5;
      bool cA  = m01 >= m23; float mA = cA ? m01 : m23; int iA = cA ? i01 : i23;
      bool cB  = m45 >= v6;  float mB = cB ? m45 : v6;  int iB = cB ? i45 : 6;
      bool cF  = mA >= mB;   float best = cF ? mA : mB; int bi = cF ? iA : iB;
      if (j < 7) bp[t * 8 + j] = (unsigned char)bi;
      fv = best + fe[t * 7 + jc];
    }
    float term = fv + trans[42 + jc];    // transitions[END=6][j]
    float best = rdlane_f32(term, 0); int btag = 0;
    #pragma unroll
    for (int i = 1; i < 7; ++i) {
      float ti = rdlane_f32(term, i);
      if (ti > best) { best = ti; btag = i; }
    }
    if (j == 0) {
      out[0] = best;
      bt[31] = (unsigned char)btag;      // tag at t = 2047
    }
  }
  __syncthreads();

  // Phase A: per-segment composed maps (32 segments x 7 entry tags)
  {
    const int s = tid >> 3, j = tid & 7;
    if (s < 32 && j < 7) {
      int g = j;
      for (int t = s * 64 + 63; t >= s * 64; --t) g = bp[t * 8 + g];
      G[s * 8 + j] = (unsigned char)g;   // tag at 64s-1 given tag j at 64s+63
    }
  }
  __syncthreads();

  // Phase B: boundary tags, serial over 32 segments
  if (tid == 0) {
    int x = bt[31];
    for (int s = 31; s >= 1; --s) { x = G[s * 8 + x]; bt[s - 1] = (unsigned char)x; }
  }
  __syncthreads();

  // Phase C: parallel rewalk, one lane per segment
  if (tid < 32) {
    const int s = tid;
    int tag = bt[s];
    for (int t = s * 64 + 63; t >= s * 64; --t) {
      out[1 + t] = (float)tag;
      tag = bp[t * 8 + tag];
    }
  }
}

// ---------- host ----------
extern "C" void kernel_launch(void* const* d_in, const int* in_sizes, int n_in,
                              void* d_out, int out_size, void* d_ws, size_t ws_size,
                              hipStream_t stream) {
  const int*   words = (const int*)d_in[0];
  const float* embed = (const float*)d_in[1];
  const float* Wih_f = (const float*)d_in[2];
  const float* Whh_f = (const float*)d_in[3];
  const float* bih_f = (const float*)d_in[4];
  const float* bhh_f = (const float*)d_in[5];
  const float* Wih_b = (const float*)d_in[6];
  const float* Whh_b = (const float*)d_in[7];
  const float* bih_b = (const float*)d_in[8];
  const float* bhh_b = (const float*)d_in[9];
  const float* Wout  = (const float*)d_in[10];
  const float* bout  = (const float*)d_in[11];
  const float* trans = (const float*)d_in[12];
  const float* h0    = (const float*)d_in[13];
  const float* c0    = (const float*)d_in[14];

  float* ws = (float*)d_ws;
  float* XW = ws;                        // 2*2048*1024           = 4,194,304 f
  float* HS = ws + 4194304;              // 2*2048*256            = 1,048,576 f
  float* XS = ws + 5242880;              // 2048*256              =   524,288 f
  float* FE = ws + 5767168;              // 2048*7                =    14,336 f
  u32*   WP = (u32*)(ws + 5781504);      // 262,144 dwords

  pack_whh<<<1024, 256, 0, stream>>>(Whh_f, Whh_b, WP);
  gather_kernel<<<T_LEN, 256, 0, stream>>>(words, embed, XS);
  dim3 ggrid(T_LEN / 32, 1024 / 128, 2);
  gemm_xw<<<ggrid, 256, 0, stream>>>(XS, Wih_f, Wih_b, bih_f, bhh_f, bih_b, bhh_b, XW);
  lstm_seq<<<2, 512, SM_TOT * 4, stream>>>(XW, HS, WP, h0, c0);
  feats_kernel<<<128, 128, 0, stream>>>(HS, Wout, bout, FE);
  viterbi_kernel<<<1, 256, 74048, stream>>>(FE, trans, (float*)d_out);
}

// Round 5
// 2615.409 us; speedup vs baseline: 3.5433x; 1.5904x over previous
//
#include <hip/hip_runtime.h>

typedef unsigned int u32;

#define T_LEN 2048
#define NEG (-10000.0f)
#define WSCALE 2032.0f
#define HSCALE 127.0f
#define SCALE_INV (1.0f / (2032.0f * 127.0f))

// ---------- helpers ----------
__device__ __forceinline__ int sdot4(u32 a, u32 b, int c) {
#if __has_builtin(__builtin_amdgcn_sdot4)
  return __builtin_amdgcn_sdot4((int)a, (int)b, c, false);
#else
  int r = c;
  r += (int)(signed char)(a)       * (int)(signed char)(b);
  r += (int)(signed char)(a >> 8)  * (int)(signed char)(b >> 8);
  r += (int)(signed char)(a >> 16) * (int)(signed char)(b >> 16);
  r += (int)(signed char)(a >> 24) * (int)(signed char)(b >> 24);
  return r;
#endif
}

__device__ __forceinline__ u32 rdlane_u32(u32 v, int lane) {
#if __has_builtin(__builtin_amdgcn_readlane)
  return (u32)__builtin_amdgcn_readlane((int)v, lane);
#else
  return (u32)__shfl((int)v, lane);
#endif
}

__device__ __forceinline__ float rdlane_f32(float v, int lane) {
  return __builtin_bit_cast(float, rdlane_u32(__builtin_bit_cast(u32, v), lane));
}

// ---------- kernel 1: pack Whh (both dirs) into int8 quads ----------
// Row r (gate row), k in [0,256). dword m = 4q+j covers k = 4m..4m+3.
// dest layout: WP[((d*16+q)*1024 + r)*4 + j]  (uint4 per row-quad, coalesced)
__global__ void pack_whh_i8(const float* __restrict__ Wf,
                            const float* __restrict__ Wb,
                            u32* __restrict__ WP) {
  int idx = blockIdx.x * 256 + threadIdx.x;   // < 131072
  int d   = idx >> 16;
  int rem = idx & 65535;
  int q   = rem >> 12;
  int r   = (rem >> 2) & 1023;
  int j   = rem & 3;
  const float* W = d ? Wb : Wf;
  float4 v = *(const float4*)&W[r * 256 + q * 16 + j * 4];
  int b0 = (int)rintf(fminf(fmaxf(v.x * WSCALE, -127.f), 127.f));
  int b1 = (int)rintf(fminf(fmaxf(v.y * WSCALE, -127.f), 127.f));
  int b2 = (int)rintf(fminf(fmaxf(v.z * WSCALE, -127.f), 127.f));
  int b3 = (int)rintf(fminf(fmaxf(v.w * WSCALE, -127.f), 127.f));
  WP[((d * 16 + q) * 1024 + r) * 4 + j] =
      (u32)(b0 & 255) | ((u32)(b1 & 255) << 8) |
      ((u32)(b2 & 255) << 16) | ((u32)(b3 & 255) << 24);
}

// ---------- kernel 2: embedding gather ----------
__global__ void gather_kernel(const int* __restrict__ words,
                              const float* __restrict__ embed,
                              float* __restrict__ xs) {
  int t = blockIdx.x;
  int k = threadIdx.x;
  xs[t * 256 + k] = embed[(size_t)words[t] * 256 + k];
}

// ---------- kernel 3: XW[d][t][g] = xs[t]·Wih_d[g] + bih[g] + bhh[g] ----------
__global__ __launch_bounds__(256) void gemm_xw(
    const float* __restrict__ xs,
    const float* __restrict__ Wf, const float* __restrict__ Wb,
    const float* __restrict__ bihf, const float* __restrict__ bhhf,
    const float* __restrict__ bihb, const float* __restrict__ bhhb,
    float* __restrict__ XW) {
  __shared__ float lx[32 * 256];
  __shared__ float lw[32 * 132];
  const int tid = threadIdx.x;
  const int t0 = blockIdx.x * 32;
  const int g0 = blockIdx.y * 128;
  const int d  = blockIdx.z;
  const float* W = d ? Wb : Wf;

  #pragma unroll 4
  for (int r = 0; r < 32; ++r) lx[r * 256 + tid] = xs[(t0 + r) * 256 + tid];

  const int tg = tid & 31, tt = tid >> 5;
  float acc[4][4] = {};

  for (int kc = 0; kc < 8; ++kc) {
    __syncthreads();
    #pragma unroll
    for (int r2 = 0; r2 < 16; ++r2) {
      int gg = r2 * 8 + (tid >> 5);
      int k  = tid & 31;
      lw[k * 132 + gg] = W[(g0 + gg) * 256 + kc * 32 + k];
    }
    __syncthreads();
    #pragma unroll
    for (int k = 0; k < 32; ++k) {
      float4 wv = *(const float4*)&lw[k * 132 + tg * 4];
      #pragma unroll
      for (int a = 0; a < 4; ++a) {
        float xa = lx[(tt * 4 + a) * 256 + kc * 32 + k];
        acc[a][0] = fmaf(xa, wv.x, acc[a][0]);
        acc[a][1] = fmaf(xa, wv.y, acc[a][1]);
        acc[a][2] = fmaf(xa, wv.z, acc[a][2]);
        acc[a][3] = fmaf(xa, wv.w, acc[a][3]);
      }
    }
  }
  const float* bih = d ? bihb : bihf;
  const float* bhh = d ? bhhb : bhhf;
  int gcol = g0 + tg * 4;
  float4 bb;
  bb.x = bih[gcol + 0] + bhh[gcol + 0];
  bb.y = bih[gcol + 1] + bhh[gcol + 1];
  bb.z = bih[gcol + 2] + bhh[gcol + 2];
  bb.w = bih[gcol + 3] + bhh[gcol + 3];
  #pragma unroll
  for (int a = 0; a < 4; ++a) {
    float4 o;
    o.x = acc[a][0] + bb.x;
    o.y = acc[a][1] + bb.y;
    o.z = acc[a][2] + bb.z;
    o.w = acc[a][3] + bb.w;
    *(float4*)&XW[((size_t)d * T_LEN + t0 + tt * 4 + a) * 1024 + gcol] = o;
  }
}

// ---------- kernel 4: the sequential bidirectional LSTM (int8 dot4) ----------
// grid = 2 (d), block = 512; thread owns gate rows tid and tid+512.
// All 128 weight dwords per thread register-resident. h broadcast: one LDS
// b32 per thread + v_readlane; dot via v_dot4_i32_i8 (exact i32 accum).
__global__ void __launch_bounds__(512)
__attribute__((amdgpu_waves_per_eu(2, 2)))
lstm_seq(
    const float* __restrict__ XW, float* __restrict__ HS,
    const u32* __restrict__ wpack,
    const float* __restrict__ h0, const float* __restrict__ c0) {
  __shared__ u32   H8[64];      // 256 h values as i8, dword m = h[4m..4m+3]
  __shared__ float GT[1024];    // gate preactivations
  const int tid = threadIdx.x;
  const int d = blockIdx.x;
  const int lane = tid & 63;

  uint4 w0[16], w1[16];
  const uint4* wr = (const uint4*)wpack;
  #pragma unroll
  for (int q = 0; q < 16; ++q) {
    w0[q] = wr[(d * 16 + q) * 1024 + tid];
    w1[q] = wr[(d * 16 + q) * 1024 + tid + 512];
  }

  float c = 0.0f, h = 0.0f;
  if (tid < 256) {
    c = c0[d * 256 + tid];
    h = h0[d * 256 + tid];
    int hi = (int)rintf(fminf(fmaxf(h, -1.0f), 1.0f) * HSCALE);
    int h1v = __shfl_down(hi, 1);
    int h2v = __shfl_down(hi, 2);
    int h3v = __shfl_down(hi, 3);
    if (!(tid & 3))
      H8[tid >> 2] = (u32)(hi & 255) | ((u32)(h1v & 255) << 8) |
                     ((u32)(h2v & 255) << 16) | ((u32)(h3v & 255) << 24);
  }
  __syncthreads();
  u32 hA = H8[lane];            // dword `lane` of packed h

  const int delta = d ? -1024 : 1024;
  const float* xwp = XW + ((size_t)d * T_LEN + (d ? (T_LEN - 1) : 0)) * 1024 + tid;
  float xw0c = xwp[0], xw1c = xwp[512];

  for (int s = 0; s < T_LEN; ++s) {
    float xw0n = 0.0f, xw1n = 0.0f;
    if (s < T_LEN - 1) { xwp += delta; xw0n = xwp[0]; xw1n = xwp[512]; }

    int a0 = 0, b0 = 0;   // two accumulator chains for row r0
    int a1 = 0, b1 = 0;   // two accumulator chains for row r1
    #pragma unroll
    for (int q = 0; q < 16; ++q) {
      u32 s0 = rdlane_u32(hA, 4 * q + 0);
      u32 s1 = rdlane_u32(hA, 4 * q + 1);
      u32 s2 = rdlane_u32(hA, 4 * q + 2);
      u32 s3 = rdlane_u32(hA, 4 * q + 3);
      a0 = sdot4(w0[q].x, s0, a0);
      a1 = sdot4(w1[q].x, s0, a1);
      b0 = sdot4(w0[q].y, s1, b0);
      b1 = sdot4(w1[q].y, s1, b1);
      a0 = sdot4(w0[q].z, s2, a0);
      a1 = sdot4(w1[q].z, s2, a1);
      b0 = sdot4(w0[q].w, s3, b0);
      b1 = sdot4(w1[q].w, s3, b1);
    }
    GT[tid]       = fmaf((float)(a0 + b0), SCALE_INV, xw0c);
    GT[tid + 512] = fmaf((float)(a1 + b1), SCALE_INV, xw1c);
    __syncthreads();

    const int t = d ? (T_LEN - 1 - s) : s;
    if (tid < 256) {
      float gi = GT[tid];
      float gf = GT[256 + tid];
      float gc = GT[512 + tid];
      float go = GT[768 + tid];
      gi = 1.0f / (1.0f + __expf(-gi));
      gf = 1.0f / (1.0f + __expf(-gf));
      go = 1.0f / (1.0f + __expf(-go));
      gc = 1.0f - 2.0f / (__expf(2.0f * gc) + 1.0f);   // tanh
      c = gf * c + gi * gc;
      float th = 1.0f - 2.0f / (__expf(2.0f * c) + 1.0f);
      h = go * th;
      HS[((size_t)d * T_LEN + t) * 256 + tid] = h;
      int hi = (int)rintf(h * HSCALE);
      int h1v = __shfl_down(hi, 1);
      int h2v = __shfl_down(hi, 2);
      int h3v = __shfl_down(hi, 3);
      if (!(tid & 3))
        H8[tid >> 2] = (u32)(hi & 255) | ((u32)(h1v & 255) << 8) |
                       ((u32)(h2v & 255) << 16) | ((u32)(h3v & 255) << 24);
    }
    __syncthreads();
    hA = H8[lane];
    xw0c = xw0n;
    xw1c = xw1n;
  }
}

// ---------- kernel 5: feats[t][n] = [hs_f ; hs_b]·W_out[n] + b_out[n] ----------
__global__ void feats_kernel(const float* __restrict__ hs,
                             const float* __restrict__ wout,
                             const float* __restrict__ bout,
                             float* __restrict__ feats) {
  __shared__ float lf[16 * 257];
  __shared__ float lb[16 * 257];
  const int tid = threadIdx.x;   // 128
  const int t0 = blockIdx.x * 16;
  for (int i = tid; i < 16 * 256; i += 128) {
    int r = i >> 8, k = i & 255;
    lf[r * 257 + k] = hs[(size_t)(t0 + r) * 256 + k];
    lb[r * 257 + k] = hs[(size_t)T_LEN * 256 + (size_t)(t0 + r) * 256 + k];
  }
  __syncthreads();
  const int tl = tid >> 3, n = tid & 7;
  if (n < 7) {
    float acc = bout[n];
    #pragma unroll 8
    for (int k = 0; k < 256; ++k) acc = fmaf(lf[tl * 257 + k], wout[n * 512 + k], acc);
    #pragma unroll 8
    for (int k = 0; k < 256; ++k) acc = fmaf(lb[tl * 257 + k], wout[n * 512 + 256 + k], acc);
    feats[(t0 + tl) * 7 + n] = acc;
  }
}

// ---------- kernel 6: Viterbi decode ----------
// 1 block, 256 threads. feats in LDS; forward on wave 0 via readlane;
// blocked backtrack: 32 segment maps (parallel) + boundary chain + rewalk.
// Dyn LDS bytes: fe 57344 | bp 16384 | G 256 | bt 64  => 74048
__global__ __launch_bounds__(256) void viterbi_kernel(
    const float* __restrict__ feats,
    const float* __restrict__ trans,
    float* __restrict__ out) {
  extern __shared__ char vsm[];
  float*         fe = (float*)vsm;                       // [T_LEN*7]
  unsigned char* bp = (unsigned char*)(vsm + 57344);     // [T_LEN][8]
  unsigned char* G  = (unsigned char*)(vsm + 73728);     // [32][8]
  unsigned char* bt = (unsigned char*)(vsm + 73984);     // [32]
  const int tid = threadIdx.x;

  for (int i = tid; i < T_LEN * 7; i += 256) fe[i] = feats[i];
  __syncthreads();

  if (tid < 64) {
    const int j  = tid;
    const int jc = (j < 7) ? j : 0;
    float Trow[7];
    #pragma unroll
    for (int i = 0; i < 7; ++i) Trow[i] = trans[jc * 7 + i];
    float fv = (j == 5) ? 0.0f : NEG;    // START = 5
    for (int t = 0; t < T_LEN; ++t) {
      float f0 = rdlane_f32(fv, 0), f1 = rdlane_f32(fv, 1), f2 = rdlane_f32(fv, 2),
            f3 = rdlane_f32(fv, 3), f4 = rdlane_f32(fv, 4), f5 = rdlane_f32(fv, 5),
            f6 = rdlane_f32(fv, 6);
      float v0 = f0 + Trow[0], v1 = f1 + Trow[1], v2 = f2 + Trow[2],
            v3 = f3 + Trow[3], v4 = f4 + Trow[4], v5 = f5 + Trow[5],
            v6 = f6 + Trow[6];
      // first-max argmax tree (lower index wins ties), matches jnp.argmax
      bool c01 = v0 >= v1;  float m01 = c01 ? v0 : v1;  int i01 = c01 ? 0 : 1;
      bool c23 = v2 >= v3;  float m23 = c23 ? v2 : v3;  int i23 = c23 ? 2 : 3;
      bool c45 = v4 >= v5;  float m45 = c45 ? v4 : v5;  int i45 = c45 ? 4 : 5;
      bool cA  = m01 >= m23; float mA = cA ? m01 : m23; int iA = cA ? i01 : i23;
      bool cB  = m45 >= v6;  float mB = cB ? m45 : v6;  int iB = cB ? i45 : 6;
      bool cF  = mA >= mB;   float best = cF ? mA : mB; int bi = cF ? iA : iB;
      if (j < 7) bp[t * 8 + j] = (unsigned char)bi;
      fv = best + fe[t * 7 + jc];
    }
    float term = fv + trans[42 + jc];    // transitions[END=6][j]
    float best = rdlane_f32(term, 0); int btag = 0;
    #pragma unroll
    for (int i = 1; i < 7; ++i) {
      float ti = rdlane_f32(term, i);
      if (ti > best) { best = ti; btag = i; }
    }
    if (j == 0) {
      out[0] = best;
      bt[31] = (unsigned char)btag;      // tag at t = 2047
    }
  }
  __syncthreads();

  // Phase A: per-segment composed maps (32 segments x 7 entry tags)
  {
    const int s = tid >> 3, j = tid & 7;
    if (s < 32 && j < 7) {
      int g = j;
      for (int t = s * 64 + 63; t >= s * 64; --t) g = bp[t * 8 + g];
      G[s * 8 + j] = (unsigned char)g;   // tag at 64s-1 given tag j at 64s+63
    }
  }
  __syncthreads();

  // Phase B: boundary tags, serial over 32 segments
  if (tid == 0) {
    int x = bt[31];
    for (int s = 31; s >= 1; --s) { x = G[s * 8 + x]; bt[s - 1] = (unsigned char)x; }
  }
  __syncthreads();

  // Phase C: parallel rewalk, one lane per segment
  if (tid < 32) {
    const int s = tid;
    int tag = bt[s];
    for (int t = s * 64 + 63; t >= s * 64; --t) {
      out[1 + t] = (float)tag;
      tag = bp[t * 8 + tag];
    }
  }
}

// ---------- host ----------
extern "C" void kernel_launch(void* const* d_in, const int* in_sizes, int n_in,
                              void* d_out, int out_size, void* d_ws, size_t ws_size,
                              hipStream_t stream) {
  const int*   words = (const int*)d_in[0];
  const float* embed = (const float*)d_in[1];
  const float* Wih_f = (const float*)d_in[2];
  const float* Whh_f = (const float*)d_in[3];
  const float* bih_f = (const float*)d_in[4];
  const float* bhh_f = (const float*)d_in[5];
  const float* Wih_b = (const float*)d_in[6];
  const float* Whh_b = (const float*)d_in[7];
  const float* bih_b = (const float*)d_in[8];
  const float* bhh_b = (const float*)d_in[9];
  const float* Wout  = (const float*)d_in[10];
  const float* bout  = (const float*)d_in[11];
  const float* trans = (const float*)d_in[12];
  const float* h0    = (const float*)d_in[13];
  const float* c0    = (const float*)d_in[14];

  float* ws = (float*)d_ws;
  float* XW = ws;                        // 2*2048*1024           = 4,194,304 f
  float* HS = ws + 4194304;              // 2*2048*256            = 1,048,576 f
  float* XS = ws + 5242880;              // 2048*256              =   524,288 f
  float* FE = ws + 5767168;              // 2048*7                =    14,336 f
  u32*   WP = (u32*)(ws + 5781504);      // 131,072 dwords (int8 weights)

  pack_whh_i8<<<512, 256, 0, stream>>>(Whh_f, Whh_b, WP);
  gather_kernel<<<T_LEN, 256, 0, stream>>>(words, embed, XS);
  dim3 ggrid(T_LEN / 32, 1024 / 128, 2);
  gemm_xw<<<ggrid, 256, 0, stream>>>(XS, Wih_f, Wih_b, bih_f, bhh_f, bih_b, bhh_b, XW);
  lstm_seq<<<2, 512, 0, stream>>>(XW, HS, WP, h0, c0);
  feats_kernel<<<128, 128, 0, stream>>>(HS, Wout, bout, FE);
  viterbi_kernel<<<1, 256, 74048, stream>>>(FE, trans, (float*)d_out);
}

// Round 6
// 2568.943 us; speedup vs baseline: 3.6074x; 1.0181x over previous
//
#include <hip/hip_runtime.h>

typedef unsigned int u32;

#define T_LEN 2048
#define NEG (-10000.0f)
#define WSCALE 2032.0f
#define HSCALE 127.0f
#define SCALE_INV (1.0f / (2032.0f * 127.0f))

// ---------- helpers ----------
// v_dot4_i32_i8: acc += dot(w.i8x4, h.i8x4); h is the (single) SGPR operand,
// w is forced into an arch VGPR ("v") so weights cannot live in AGPRs.
#define DOT(acc, w, hs) \
  asm("v_dot4_i32_i8 %0, %2, %1, %0" : "+v"(acc) : "v"(w), "s"(hs))

__device__ __forceinline__ u32 rdlane_u32(u32 v, int lane) {
#if __has_builtin(__builtin_amdgcn_readlane)
  return (u32)__builtin_amdgcn_readlane((int)v, lane);
#else
  return (u32)__shfl((int)v, lane);
#endif
}

__device__ __forceinline__ float rdlane_f32(float v, int lane) {
  return __builtin_bit_cast(float, rdlane_u32(__builtin_bit_cast(u32, v), lane));
}

// Raw barrier: LDS-drain only, NO vmcnt(0) drain (global stores have no
// intra-kernel reader; global loads wait at their point of use).
__device__ __forceinline__ void block_sync_lds() {
  asm volatile("s_waitcnt lgkmcnt(0)" ::: "memory");
  __builtin_amdgcn_s_barrier();
}

// ---------- kernel 1: pack Whh (both dirs) into int8 quads ----------
// Row r (gate row), k in [0,256). dword m = 4q+j covers k = 4m..4m+3.
// dest layout: WP[((d*16+q)*1024 + r)*4 + j]  (uint4 per row-quad, coalesced)
__global__ void pack_whh_i8(const float* __restrict__ Wf,
                            const float* __restrict__ Wb,
                            u32* __restrict__ WP) {
  int idx = blockIdx.x * 256 + threadIdx.x;   // < 131072
  int d   = idx >> 16;
  int rem = idx & 65535;
  int q   = rem >> 12;
  int r   = (rem >> 2) & 1023;
  int j   = rem & 3;
  const float* W = d ? Wb : Wf;
  float4 v = *(const float4*)&W[r * 256 + q * 16 + j * 4];
  int b0 = (int)rintf(fminf(fmaxf(v.x * WSCALE, -127.f), 127.f));
  int b1 = (int)rintf(fminf(fmaxf(v.y * WSCALE, -127.f), 127.f));
  int b2 = (int)rintf(fminf(fmaxf(v.z * WSCALE, -127.f), 127.f));
  int b3 = (int)rintf(fminf(fmaxf(v.w * WSCALE, -127.f), 127.f));
  WP[((d * 16 + q) * 1024 + r) * 4 + j] =
      (u32)(b0 & 255) | ((u32)(b1 & 255) << 8) |
      ((u32)(b2 & 255) << 16) | ((u32)(b3 & 255) << 24);
}

// ---------- kernel 2: embedding gather ----------
__global__ void gather_kernel(const int* __restrict__ words,
                              const float* __restrict__ embed,
                              float* __restrict__ xs) {
  int t = blockIdx.x;
  int k = threadIdx.x;
  xs[t * 256 + k] = embed[(size_t)words[t] * 256 + k];
}

// ---------- kernel 3: XW[d][t][g] = xs[t]·Wih_d[g] + bih[g] + bhh[g] ----------
__global__ __launch_bounds__(256) void gemm_xw(
    const float* __restrict__ xs,
    const float* __restrict__ Wf, const float* __restrict__ Wb,
    const float* __restrict__ bihf, const float* __restrict__ bhhf,
    const float* __restrict__ bihb, const float* __restrict__ bhhb,
    float* __restrict__ XW) {
  __shared__ float lx[32 * 256];
  __shared__ float lw[32 * 132];
  const int tid = threadIdx.x;
  const int t0 = blockIdx.x * 32;
  const int g0 = blockIdx.y * 128;
  const int d  = blockIdx.z;
  const float* W = d ? Wb : Wf;

  #pragma unroll 4
  for (int r = 0; r < 32; ++r) lx[r * 256 + tid] = xs[(t0 + r) * 256 + tid];

  const int tg = tid & 31, tt = tid >> 5;
  float acc[4][4] = {};

  for (int kc = 0; kc < 8; ++kc) {
    __syncthreads();
    #pragma unroll
    for (int r2 = 0; r2 < 16; ++r2) {
      int gg = r2 * 8 + (tid >> 5);
      int k  = tid & 31;
      lw[k * 132 + gg] = W[(g0 + gg) * 256 + kc * 32 + k];
    }
    __syncthreads();
    #pragma unroll
    for (int k = 0; k < 32; ++k) {
      float4 wv = *(const float4*)&lw[k * 132 + tg * 4];
      #pragma unroll
      for (int a = 0; a < 4; ++a) {
        float xa = lx[(tt * 4 + a) * 256 + kc * 32 + k];
        acc[a][0] = fmaf(xa, wv.x, acc[a][0]);
        acc[a][1] = fmaf(xa, wv.y, acc[a][1]);
        acc[a][2] = fmaf(xa, wv.z, acc[a][2]);
        acc[a][3] = fmaf(xa, wv.w, acc[a][3]);
      }
    }
  }
  const float* bih = d ? bihb : bihf;
  const float* bhh = d ? bhhb : bhhf;
  int gcol = g0 + tg * 4;
  float4 bb;
  bb.x = bih[gcol + 0] + bhh[gcol + 0];
  bb.y = bih[gcol + 1] + bhh[gcol + 1];
  bb.z = bih[gcol + 2] + bhh[gcol + 2];
  bb.w = bih[gcol + 3] + bhh[gcol + 3];
  #pragma unroll
  for (int a = 0; a < 4; ++a) {
    float4 o;
    o.x = acc[a][0] + bb.x;
    o.y = acc[a][1] + bb.y;
    o.z = acc[a][2] + bb.z;
    o.w = acc[a][3] + bb.w;
    *(float4*)&XW[((size_t)d * T_LEN + t0 + tt * 4 + a) * 1024 + gcol] = o;
  }
}

// ---------- kernel 4: the sequential bidirectional LSTM (int8 dot4) ----------
// grid = 2 (d), block = 512; thread owns gate rows tid and tid+512.
// All 128 weight dwords register-resident (asm "v" pins arch VGPRs).
// h broadcast: 1 LDS b32 read + readlane (SGPR) per quad; raw barriers.
__global__ void __launch_bounds__(512)
__attribute__((amdgpu_waves_per_eu(2, 2)))
lstm_seq(
    const float* __restrict__ XW, float* __restrict__ HS,
    const u32* __restrict__ wpack,
    const float* __restrict__ h0, const float* __restrict__ c0) {
  __shared__ u32   H8[64];      // 256 h values as i8, dword m = h[4m..4m+3]
  __shared__ float GT[1024];    // gate preactivations
  const int tid = threadIdx.x;
  const int d = blockIdx.x;
  const int lane = tid & 63;

  uint4 w0[16], w1[16];
  const uint4* wr = (const uint4*)wpack;
  #pragma unroll
  for (int q = 0; q < 16; ++q) {
    w0[q] = wr[(d * 16 + q) * 1024 + tid];
    w1[q] = wr[(d * 16 + q) * 1024 + tid + 512];
  }

  float c = 0.0f, h = 0.0f;
  if (tid < 256) {
    c = c0[d * 256 + tid];
    h = h0[d * 256 + tid];
    int hi = (int)rintf(fminf(fmaxf(h, -1.0f), 1.0f) * HSCALE);
    ((unsigned char*)H8)[tid] = (unsigned char)(hi & 255);
  }
  block_sync_lds();
  u32 hA = H8[lane];            // dword `lane` of packed h

  const int delta = d ? -1024 : 1024;
  const float* xwp = XW + ((size_t)d * T_LEN + (d ? (T_LEN - 1) : 0)) * 1024 + tid;
  float xw0c = xwp[0], xw1c = xwp[512];

  for (int s = 0; s < T_LEN; ++s) {
    float xw0n = 0.0f, xw1n = 0.0f;
    if (s < T_LEN - 1) { xwp += delta; xw0n = xwp[0]; xw1n = xwp[512]; }

    int a0 = 0, b0 = 0;   // two accumulator chains for row r0
    int a1 = 0, b1 = 0;   // two accumulator chains for row r1
    {
      u32 s0 = rdlane_u32(hA, 0);
      u32 s1 = rdlane_u32(hA, 1);
      u32 s2 = rdlane_u32(hA, 2);
      u32 s3 = rdlane_u32(hA, 3);
      #pragma unroll
      for (int q = 0; q < 16; ++q) {
        u32 n0 = 0, n1 = 0, n2 = 0, n3 = 0;
        if (q < 15) {                       // prefetch next quad's broadcasts
          n0 = rdlane_u32(hA, 4 * q + 4);
          n1 = rdlane_u32(hA, 4 * q + 5);
          n2 = rdlane_u32(hA, 4 * q + 6);
          n3 = rdlane_u32(hA, 4 * q + 7);
        }
        DOT(a0, w0[q].x, s0);
        DOT(a1, w1[q].x, s0);
        DOT(b0, w0[q].y, s1);
        DOT(b1, w1[q].y, s1);
        DOT(a0, w0[q].z, s2);
        DOT(a1, w1[q].z, s2);
        DOT(b0, w0[q].w, s3);
        DOT(b1, w1[q].w, s3);
        s0 = n0; s1 = n1; s2 = n2; s3 = n3;
      }
    }
    GT[tid]       = fmaf((float)(a0 + b0), SCALE_INV, xw0c);
    GT[tid + 512] = fmaf((float)(a1 + b1), SCALE_INV, xw1c);
    block_sync_lds();

    const int t = d ? (T_LEN - 1 - s) : s;
    if (tid < 256) {
      float gi = GT[tid];
      float gf = GT[256 + tid];
      float gc = GT[512 + tid];
      float go = GT[768 + tid];
      gi = 1.0f / (1.0f + __expf(-gi));
      gf = 1.0f / (1.0f + __expf(-gf));
      go = 1.0f / (1.0f + __expf(-go));
      gc = 1.0f - 2.0f / (__expf(2.0f * gc) + 1.0f);   // tanh
      c = gf * c + gi * gc;
      float th = 1.0f - 2.0f / (__expf(2.0f * c) + 1.0f);
      h = go * th;
      HS[((size_t)d * T_LEN + t) * 256 + tid] = h;     // no reader in-kernel
      int hi = (int)rintf(h * HSCALE);                 // |h|<1, no clamp needed
      ((unsigned char*)H8)[tid] = (unsigned char)(hi & 255);
    }
    block_sync_lds();
    hA = H8[lane];
    xw0c = xw0n;
    xw1c = xw1n;
  }
}

// ---------- kernel 5: feats[t][n] = [hs_f ; hs_b]·W_out[n] + b_out[n] ----------
__global__ void feats_kernel(const float* __restrict__ hs,
                             const float* __restrict__ wout,
                             const float* __restrict__ bout,
                             float* __restrict__ feats) {
  __shared__ float lf[16 * 257];
  __shared__ float lb[16 * 257];
  const int tid = threadIdx.x;   // 128
  const int t0 = blockIdx.x * 16;
  for (int i = tid; i < 16 * 256; i += 128) {
    int r = i >> 8, k = i & 255;
    lf[r * 257 + k] = hs[(size_t)(t0 + r) * 256 + k];
    lb[r * 257 + k] = hs[(size_t)T_LEN * 256 + (size_t)(t0 + r) * 256 + k];
  }
  __syncthreads();
  const int tl = tid >> 3, n = tid & 7;
  if (n < 7) {
    float acc = bout[n];
    #pragma unroll 8
    for (int k = 0; k < 256; ++k) acc = fmaf(lf[tl * 257 + k], wout[n * 512 + k], acc);
    #pragma unroll 8
    for (int k = 0; k < 256; ++k) acc = fmaf(lb[tl * 257 + k], wout[n * 512 + 256 + k], acc);
    feats[(t0 + tl) * 7 + n] = acc;
  }
}

// ---------- kernel 6: Viterbi decode ----------
// 1 block, 256 threads. feats in LDS; forward on wave 0 via readlane;
// blocked backtrack: 32 segment maps (parallel) + boundary chain + rewalk.
// Dyn LDS bytes: fe 57344 | bp 16384 | G 256 | bt 64  => 74048
__global__ __launch_bounds__(256) void viterbi_kernel(
    const float* __restrict__ feats,
    const float* __restrict__ trans,
    float* __restrict__ out) {
  extern __shared__ char vsm[];
  float*         fe = (float*)vsm;                       // [T_LEN*7]
  unsigned char* bp = (unsigned char*)(vsm + 57344);     // [T_LEN][8]
  unsigned char* G  = (unsigned char*)(vsm + 73728);     // [32][8]
  unsigned char* bt = (unsigned char*)(vsm + 73984);     // [32]
  const int tid = threadIdx.x;

  for (int i = tid; i < T_LEN * 7; i += 256) fe[i] = feats[i];
  __syncthreads();

  if (tid < 64) {
    const int j  = tid;
    const int jc = (j < 7) ? j : 0;
    float Trow[7];
    #pragma unroll
    for (int i = 0; i < 7; ++i) Trow[i] = trans[jc * 7 + i];
    float fv = (j == 5) ? 0.0f : NEG;    // START = 5
    for (int t = 0; t < T_LEN; ++t) {
      float f0 = rdlane_f32(fv, 0), f1 = rdlane_f32(fv, 1), f2 = rdlane_f32(fv, 2),
            f3 = rdlane_f32(fv, 3), f4 = rdlane_f32(fv, 4), f5 = rdlane_f32(fv, 5),
            f6 = rdlane_f32(fv, 6);
      float v0 = f0 + Trow[0], v1 = f1 + Trow[1], v2 = f2 + Trow[2],
            v3 = f3 + Trow[3], v4 = f4 + Trow[4], v5 = f5 + Trow[5],
            v6 = f6 + Trow[6];
      // first-max argmax tree (lower index wins ties), matches jnp.argmax
      bool c01 = v0 >= v1;  float m01 = c01 ? v0 : v1;  int i01 = c01 ? 0 : 1;
      bool c23 = v2 >= v3;  float m23 = c23 ? v2 : v3;  int i23 = c23 ? 2 : 3;
      bool c45 = v4 >= v5;  float m45 = c45 ? v4 : v5;  int i45 = c45 ? 4 : 5;
      bool cA  = m01 >= m23; float mA = cA ? m01 : m23; int iA = cA ? i01 : i23;
      bool cB  = m45 >= v6;  float mB = cB ? m45 : v6;  int iB = cB ? i45 : 6;
      bool cF  = mA >= mB;   float best = cF ? mA : mB; int bi = cF ? iA : iB;
      if (j < 7) bp[t * 8 + j] = (unsigned char)bi;
      fv = best + fe[t * 7 + jc];
    }
    float term = fv + trans[42 + jc];    // transitions[END=6][j]
    float best = rdlane_f32(term, 0); int btag = 0;
    #pragma unroll
    for (int i = 1; i < 7; ++i) {
      float ti = rdlane_f32(term, i);
      if (ti > best) { best = ti; btag = i; }
    }
    if (j == 0) {
      out[0] = best;
      bt[31] = (unsigned char)btag;      // tag at t = 2047
    }
  }
  __syncthreads();

  // Phase A: per-segment composed maps (32 segments x 7 entry tags)
  {
    const int s = tid >> 3, j = tid & 7;
    if (s < 32 && j < 7) {
      int g = j;
      for (int t = s * 64 + 63; t >= s * 64; --t) g = bp[t * 8 + g];
      G[s * 8 + j] = (unsigned char)g;   // tag at 64s-1 given tag j at 64s+63
    }
  }
  __syncthreads();

  // Phase B: boundary tags, serial over 32 segments
  if (tid == 0) {
    int x = bt[31];
    for (int s = 31; s >= 1; --s) { x = G[s * 8 + x]; bt[s - 1] = (unsigned char)x; }
  }
  __syncthreads();

  // Phase C: parallel rewalk, one lane per segment
  if (tid < 32) {
    const int s = tid;
    int tag = bt[s];
    for (int t = s * 64 + 63; t >= s * 64; --t) {
      out[1 + t] = (float)tag;
      tag = bp[t * 8 + tag];
    }
  }
}

// ---------- host ----------
extern "C" void kernel_launch(void* const* d_in, const int* in_sizes, int n_in,
                              void* d_out, int out_size, void* d_ws, size_t ws_size,
                              hipStream_t stream) {
  const int*   words = (const int*)d_in[0];
  const float* embed = (const float*)d_in[1];
  const float* Wih_f = (const float*)d_in[2];
  const float* Whh_f = (const float*)d_in[3];
  const float* bih_f = (const float*)d_in[4];
  const float* bhh_f = (const float*)d_in[5];
  const float* Wih_b = (const float*)d_in[6];
  const float* Whh_b = (const float*)d_in[7];
  const float* bih_b = (const float*)d_in[8];
  const float* bhh_b = (const float*)d_in[9];
  const float* Wout  = (const float*)d_in[10];
  const float* bout  = (const float*)d_in[11];
  const float* trans = (const float*)d_in[12];
  const float* h0    = (const float*)d_in[13];
  const float* c0    = (const float*)d_in[14];

  float* ws = (float*)d_ws;
  float* XW = ws;                        // 2*2048*1024           = 4,194,304 f
  float* HS = ws + 4194304;              // 2*2048*256            = 1,048,576 f
  float* XS = ws + 5242880;              // 2048*256              =   524,288 f
  float* FE = ws + 5767168;              // 2048*7                =    14,336 f
  u32*   WP = (u32*)(ws + 5781504);      // 131,072 dwords (int8 weights)

  pack_whh_i8<<<512, 256, 0, stream>>>(Whh_f, Whh_b, WP);
  gather_kernel<<<T_LEN, 256, 0, stream>>>(words, embed, XS);
  dim3 ggrid(T_LEN / 32, 1024 / 128, 2);
  gemm_xw<<<ggrid, 256, 0, stream>>>(XS, Wih_f, Wih_b, bih_f, bhh_f, bih_b, bhh_b, XW);
  lstm_seq<<<2, 512, 0, stream>>>(XW, HS, WP, h0, c0);
  feats_kernel<<<128, 128, 0, stream>>>(HS, Wout, bout, FE);
  viterbi_kernel<<<1, 256, 74048, stream>>>(FE, trans, (float*)d_out);
}

// Round 7
// 2548.837 us; speedup vs baseline: 3.6359x; 1.0079x over previous
//
#include <hip/hip_runtime.h>

typedef unsigned int u32;

#define T_LEN 2048
#define NEG (-10000.0f)
#define WSCALE 2032.0f
#define HSCALE 127.0f
#define SCALE_INV (1.0f / (2032.0f * 127.0f))

// ---------- helpers ----------
__device__ __forceinline__ int sdot4(u32 a, u32 b, int c) {
#if __has_builtin(__builtin_amdgcn_sdot4)
  return __builtin_amdgcn_sdot4((int)a, (int)b, c, false);
#else
  int r = c;
  r += (int)(signed char)(a)       * (int)(signed char)(b);
  r += (int)(signed char)(a >> 8)  * (int)(signed char)(b >> 8);
  r += (int)(signed char)(a >> 16) * (int)(signed char)(b >> 16);
  r += (int)(signed char)(a >> 24) * (int)(signed char)(b >> 24);
  return r;
#endif
}

__device__ __forceinline__ u32 rdlane_u32(u32 v, int lane) {
#if __has_builtin(__builtin_amdgcn_readlane)
  return (u32)__builtin_amdgcn_readlane((int)v, lane);
#else
  return (u32)__shfl((int)v, lane);
#endif
}

__device__ __forceinline__ float rdlane_f32(float v, int lane) {
  return __builtin_bit_cast(float, rdlane_u32(__builtin_bit_cast(u32, v), lane));
}

// Raw barrier: LDS-drain only (guarantees prior LDS reads/writes complete),
// no vmcnt(0) drain of global loads/stores.
__device__ __forceinline__ void block_sync_lds() {
  asm volatile("s_waitcnt lgkmcnt(0)" ::: "memory");
  __builtin_amdgcn_s_barrier();
}

// ---------- kernel 1: pack Whh (both dirs) into int8 quads ----------
// Cell c, gate G (0=i,1=f,2=g,3=o): source row r = G*256+c.
// dest uint4 index: ((d*4+G)*16 + q4)*256 + c  (16 uint4 per gate-row)
__global__ void pack_whh_i8(const float* __restrict__ Wf,
                            const float* __restrict__ Wb,
                            u32* __restrict__ WP) {
  int idx = blockIdx.x * 256 + threadIdx.x;   // < 131072
  int d   = idx >> 16;
  int G   = (idx >> 14) & 3;
  int q4  = (idx >> 10) & 15;
  int c   = (idx >> 2) & 255;
  int j   = idx & 3;
  const float* W = d ? Wb : Wf;
  float4 v = *(const float4*)&W[(G * 256 + c) * 256 + q4 * 16 + j * 4];
  int b0 = (int)rintf(fminf(fmaxf(v.x * WSCALE, -127.f), 127.f));
  int b1 = (int)rintf(fminf(fmaxf(v.y * WSCALE, -127.f), 127.f));
  int b2 = (int)rintf(fminf(fmaxf(v.z * WSCALE, -127.f), 127.f));
  int b3 = (int)rintf(fminf(fmaxf(v.w * WSCALE, -127.f), 127.f));
  WP[(((d * 4 + G) * 16 + q4) * 256 + c) * 4 + j] =
      (u32)(b0 & 255) | ((u32)(b1 & 255) << 8) |
      ((u32)(b2 & 255) << 16) | ((u32)(b3 & 255) << 24);
}

// ---------- kernel 2: embedding gather ----------
__global__ void gather_kernel(const int* __restrict__ words,
                              const float* __restrict__ embed,
                              float* __restrict__ xs) {
  int t = blockIdx.x;
  int k = threadIdx.x;
  xs[t * 256 + k] = embed[(size_t)words[t] * 256 + k];
}

// ---------- kernel 3: XW[d][t][g] = xs[t]·Wih_d[g] + bih[g] + bhh[g] ----------
__global__ __launch_bounds__(256) void gemm_xw(
    const float* __restrict__ xs,
    const float* __restrict__ Wf, const float* __restrict__ Wb,
    const float* __restrict__ bihf, const float* __restrict__ bhhf,
    const float* __restrict__ bihb, const float* __restrict__ bhhb,
    float* __restrict__ XW) {
  __shared__ float lx[32 * 256];
  __shared__ float lw[32 * 132];
  const int tid = threadIdx.x;
  const int t0 = blockIdx.x * 32;
  const int g0 = blockIdx.y * 128;
  const int d  = blockIdx.z;
  const float* W = d ? Wb : Wf;

  #pragma unroll 4
  for (int r = 0; r < 32; ++r) lx[r * 256 + tid] = xs[(t0 + r) * 256 + tid];

  const int tg = tid & 31, tt = tid >> 5;
  float acc[4][4] = {};

  for (int kc = 0; kc < 8; ++kc) {
    __syncthreads();
    #pragma unroll
    for (int r2 = 0; r2 < 16; ++r2) {
      int gg = r2 * 8 + (tid >> 5);
      int k  = tid & 31;
      lw[k * 132 + gg] = W[(g0 + gg) * 256 + kc * 32 + k];
    }
    __syncthreads();
    #pragma unroll
    for (int k = 0; k < 32; ++k) {
      float4 wv = *(const float4*)&lw[k * 132 + tg * 4];
      #pragma unroll
      for (int a = 0; a < 4; ++a) {
        float xa = lx[(tt * 4 + a) * 256 + kc * 32 + k];
        acc[a][0] = fmaf(xa, wv.x, acc[a][0]);
        acc[a][1] = fmaf(xa, wv.y, acc[a][1]);
        acc[a][2] = fmaf(xa, wv.z, acc[a][2]);
        acc[a][3] = fmaf(xa, wv.w, acc[a][3]);
      }
    }
  }
  const float* bih = d ? bihb : bihf;
  const float* bhh = d ? bhhb : bhhf;
  int gcol = g0 + tg * 4;
  float4 bb;
  bb.x = bih[gcol + 0] + bhh[gcol + 0];
  bb.y = bih[gcol + 1] + bhh[gcol + 1];
  bb.z = bih[gcol + 2] + bhh[gcol + 2];
  bb.w = bih[gcol + 3] + bhh[gcol + 3];
  #pragma unroll
  for (int a = 0; a < 4; ++a) {
    float4 o;
    o.x = acc[a][0] + bb.x;
    o.y = acc[a][1] + bb.y;
    o.z = acc[a][2] + bb.z;
    o.w = acc[a][3] + bb.w;
    *(float4*)&XW[((size_t)d * T_LEN + t0 + tt * 4 + a) * 1024 + gcol] = o;
  }
}

// ---------- kernel 4: the sequential bidirectional LSTM (int8 dot4) ----------
// grid = 2 (d), block = 256; thread c owns ALL FOUR gate rows of cell c:
// 256 int8 weight dwords register-resident (AGPR+VGPR unified file,
// waves_per_eu(1,1) -> 512-reg budget). No gate exchange, one barrier/step,
// H8 double-buffered. h broadcast via readlane.
__global__ void __launch_bounds__(256)
__attribute__((amdgpu_waves_per_eu(1, 1)))
lstm_seq(
    const float* __restrict__ XW, float* __restrict__ HS,
    const u32* __restrict__ wpack,
    const float* __restrict__ h0, const float* __restrict__ c0) {
  __shared__ u32 H8[2][64];     // double-buffered packed h (256 x i8)
  const int tid = threadIdx.x;  // cell index c
  const int d = blockIdx.x;
  const int lane = tid & 63;

  // load 4 x 64 weight dwords into registers (static indices only)
  u32 wIv[64], wFv[64], wGv[64], wOv[64];
  {
    const uint4* wr = (const uint4*)wpack;
    #pragma unroll
    for (int q4 = 0; q4 < 16; ++q4) {
      uint4 t;
      t = wr[((d * 4 + 0) * 16 + q4) * 256 + tid];
      wIv[q4 * 4 + 0] = t.x; wIv[q4 * 4 + 1] = t.y;
      wIv[q4 * 4 + 2] = t.z; wIv[q4 * 4 + 3] = t.w;
      t = wr[((d * 4 + 1) * 16 + q4) * 256 + tid];
      wFv[q4 * 4 + 0] = t.x; wFv[q4 * 4 + 1] = t.y;
      wFv[q4 * 4 + 2] = t.z; wFv[q4 * 4 + 3] = t.w;
      t = wr[((d * 4 + 2) * 16 + q4) * 256 + tid];
      wGv[q4 * 4 + 0] = t.x; wGv[q4 * 4 + 1] = t.y;
      wGv[q4 * 4 + 2] = t.z; wGv[q4 * 4 + 3] = t.w;
      t = wr[((d * 4 + 3) * 16 + q4) * 256 + tid];
      wOv[q4 * 4 + 0] = t.x; wOv[q4 * 4 + 1] = t.y;
      wOv[q4 * 4 + 2] = t.z; wOv[q4 * 4 + 3] = t.w;
    }
  }

  float c = c0[d * 256 + tid];
  float h = h0[d * 256 + tid];
  {
    int hi = (int)rintf(fminf(fmaxf(h, -1.0f), 1.0f) * HSCALE);
    ((unsigned char*)&H8[0][0])[tid] = (unsigned char)(hi & 255);
  }
  block_sync_lds();
  u32 hA = H8[0][lane];

  const int delta = d ? -1024 : 1024;
  const float* xwp = XW + ((size_t)d * T_LEN + (d ? (T_LEN - 1) : 0)) * 1024 + tid;
  float xi = xwp[0], xf = xwp[256], xg = xwp[512], xo = xwp[768];

  for (int s = 0; s < T_LEN; ++s) {
    float ni = 0.f, nf = 0.f, ng = 0.f, no = 0.f;
    if (s < T_LEN - 1) {
      xwp += delta;
      ni = xwp[0]; nf = xwp[256]; ng = xwp[512]; no = xwp[768];
    }

    int aI = 0, aF = 0, aG = 0, aO = 0;   // 4 independent chains
    #pragma unroll
    for (int q = 0; q < 64; ++q) {
      u32 sv = rdlane_u32(hA, q);
      aI = sdot4(wIv[q], sv, aI);
      aF = sdot4(wFv[q], sv, aF);
      aG = sdot4(wGv[q], sv, aG);
      aO = sdot4(wOv[q], sv, aO);
    }

    // tail: all in-register, every thread owns its cell
    float gi = fmaf((float)aI, SCALE_INV, xi);
    float gf = fmaf((float)aF, SCALE_INV, xf);
    float gc = fmaf((float)aG, SCALE_INV, xg);
    float go = fmaf((float)aO, SCALE_INV, xo);
    gi = 1.0f / (1.0f + __expf(-gi));
    gf = 1.0f / (1.0f + __expf(-gf));
    go = 1.0f / (1.0f + __expf(-go));
    gc = 1.0f - 2.0f / (__expf(2.0f * gc) + 1.0f);   // tanh
    c = gf * c + gi * gc;
    float th = 1.0f - 2.0f / (__expf(2.0f * c) + 1.0f);
    h = go * th;

    const int t = d ? (T_LEN - 1 - s) : s;
    HS[((size_t)d * T_LEN + t) * 256 + tid] = h;     // no reader in-kernel

    int hi = (int)rintf(h * HSCALE);                 // |h|<1, no clamp needed
    const int wbuf = (s + 1) & 1;
    ((unsigned char*)&H8[wbuf][0])[tid] = (unsigned char)(hi & 255);
    block_sync_lds();                                // one barrier per step
    hA = H8[wbuf][lane];
    xi = ni; xf = nf; xg = ng; xo = no;
  }
}

// ---------- kernel 5: feats[t][n] = [hs_f ; hs_b]·W_out[n] + b_out[n] ----------
__global__ void feats_kernel(const float* __restrict__ hs,
                             const float* __restrict__ wout,
                             const float* __restrict__ bout,
                             float* __restrict__ feats) {
  __shared__ float lf[16 * 257];
  __shared__ float lb[16 * 257];
  const int tid = threadIdx.x;   // 128
  const int t0 = blockIdx.x * 16;
  for (int i = tid; i < 16 * 256; i += 128) {
    int r = i >> 8, k = i & 255;
    lf[r * 257 + k] = hs[(size_t)(t0 + r) * 256 + k];
    lb[r * 257 + k] = hs[(size_t)T_LEN * 256 + (size_t)(t0 + r) * 256 + k];
  }
  __syncthreads();
  const int tl = tid >> 3, n = tid & 7;
  if (n < 7) {
    float acc = bout[n];
    #pragma unroll 8
    for (int k = 0; k < 256; ++k) acc = fmaf(lf[tl * 257 + k], wout[n * 512 + k], acc);
    #pragma unroll 8
    for (int k = 0; k < 256; ++k) acc = fmaf(lb[tl * 257 + k], wout[n * 512 + 256 + k], acc);
    feats[(t0 + tl) * 7 + n] = acc;
  }
}

// ---------- kernel 6: Viterbi decode ----------
// 1 block, 256 threads. feats in LDS; forward on wave 0 via readlane;
// blocked backtrack: 32 segment maps (parallel) + boundary chain + rewalk.
// Dyn LDS bytes: fe 57344 | bp 16384 | G 256 | bt 64  => 74048
__global__ __launch_bounds__(256) void viterbi_kernel(
    const float* __restrict__ feats,
    const float* __restrict__ trans,
    float* __restrict__ out) {
  extern __shared__ char vsm[];
  float*         fe = (float*)vsm;                       // [T_LEN*7]
  unsigned char* bp = (unsigned char*)(vsm + 57344);     // [T_LEN][8]
  unsigned char* G  = (unsigned char*)(vsm + 73728);     // [32][8]
  unsigned char* bt = (unsigned char*)(vsm + 73984);     // [32]
  const int tid = threadIdx.x;

  for (int i = tid; i < T_LEN * 7; i += 256) fe[i] = feats[i];
  __syncthreads();

  if (tid < 64) {
    const int j  = tid;
    const int jc = (j < 7) ? j : 0;
    float Trow[7];
    #pragma unroll
    for (int i = 0; i < 7; ++i) Trow[i] = trans[jc * 7 + i];
    float fv = (j == 5) ? 0.0f : NEG;    // START = 5
    for (int t = 0; t < T_LEN; ++t) {
      float f0 = rdlane_f32(fv, 0), f1 = rdlane_f32(fv, 1), f2 = rdlane_f32(fv, 2),
            f3 = rdlane_f32(fv, 3), f4 = rdlane_f32(fv, 4), f5 = rdlane_f32(fv, 5),
            f6 = rdlane_f32(fv, 6);
      float v0 = f0 + Trow[0], v1 = f1 + Trow[1], v2 = f2 + Trow[2],
            v3 = f3 + Trow[3], v4 = f4 + Trow[4], v5 = f5 + Trow[5],
            v6 = f6 + Trow[6];
      // first-max argmax tree (lower index wins ties), matches jnp.argmax
      bool c01 = v0 >= v1;  float m01 = c01 ? v0 : v1;  int i01 = c01 ? 0 : 1;
      bool c23 = v2 >= v3;  float m23 = c23 ? v2 : v3;  int i23 = c23 ? 2 : 3;
      bool c45 = v4 >= v5;  float m45 = c45 ? v4 : v5;  int i45 = c45 ? 4 : 5;
      bool cA  = m01 >= m23; float mA = cA ? m01 : m23; int iA = cA ? i01 : i23;
      bool cB  = m45 >= v6;  float mB = cB ? m45 : v6;  int iB = cB ? i45 : 6;
      bool cF  = mA >= mB;   float best = cF ? mA : mB; int bi = cF ? iA : iB;
      if (j < 7) bp[t * 8 + j] = (unsigned char)bi;
      fv = best + fe[t * 7 + jc];
    }
    float term = fv + trans[42 + jc];    // transitions[END=6][j]
    float best = rdlane_f32(term, 0); int btag = 0;
    #pragma unroll
    for (int i = 1; i < 7; ++i) {
      float ti = rdlane_f32(term, i);
      if (ti > best) { best = ti; btag = i; }
    }
    if (j == 0) {
      out[0] = best;
      bt[31] = (unsigned char)btag;      // tag at t = 2047
    }
  }
  __syncthreads();

  // Phase A: per-segment composed maps (32 segments x 7 entry tags)
  {
    const int s = tid >> 3, j = tid & 7;
    if (s < 32 && j < 7) {
      int g = j;
      for (int t = s * 64 + 63; t >= s * 64; --t) g = bp[t * 8 + g];
      G[s * 8 + j] = (unsigned char)g;   // tag at 64s-1 given tag j at 64s+63
    }
  }
  __syncthreads();

  // Phase B: boundary tags, serial over 32 segments
  if (tid == 0) {
    int x = bt[31];
    for (int s = 31; s >= 1; --s) { x = G[s * 8 + x]; bt[s - 1] = (unsigned char)x; }
  }
  __syncthreads();

  // Phase C: parallel rewalk, one lane per segment
  if (tid < 32) {
    const int s = tid;
    int tag = bt[s];
    for (int t = s * 64 + 63; t >= s * 64; --t) {
      out[1 + t] = (float)tag;
      tag = bp[t * 8 + tag];
    }
  }
}

// ---------- host ----------
extern "C" void kernel_launch(void* const* d_in, const int* in_sizes, int n_in,
                              void* d_out, int out_size, void* d_ws, size_t ws_size,
                              hipStream_t stream) {
  const int*   words = (const int*)d_in[0];
  const float* embed = (const float*)d_in[1];
  const float* Wih_f = (const float*)d_in[2];
  const float* Whh_f = (const float*)d_in[3];
  const float* bih_f = (const float*)d_in[4];
  const float* bhh_f = (const float*)d_in[5];
  const float* Wih_b = (const float*)d_in[6];
  const float* Whh_b = (const float*)d_in[7];
  const float* bih_b = (const float*)d_in[8];
  const float* bhh_b = (const float*)d_in[9];
  const float* Wout  = (const float*)d_in[10];
  const float* bout  = (const float*)d_in[11];
  const float* trans = (const float*)d_in[12];
  const float* h0    = (const float*)d_in[13];
  const float* c0    = (const float*)d_in[14];

  float* ws = (float*)d_ws;
  float* XW = ws;                        // 2*2048*1024           = 4,194,304 f
  float* HS = ws + 4194304;              // 2*2048*256            = 1,048,576 f
  float* XS = ws + 5242880;              // 2048*256              =   524,288 f
  float* FE = ws + 5767168;              // 2048*7                =    14,336 f
  u32*   WP = (u32*)(ws + 5781504);      // 131,072 dwords (int8 weights)

  pack_whh_i8<<<512, 256, 0, stream>>>(Whh_f, Whh_b, WP);
  gather_kernel<<<T_LEN, 256, 0, stream>>>(words, embed, XS);
  dim3 ggrid(T_LEN / 32, 1024 / 128, 2);
  gemm_xw<<<ggrid, 256, 0, stream>>>(XS, Wih_f, Wih_b, bih_f, bhh_f, bih_b, bhh_b, XW);
  lstm_seq<<<2, 256, 0, stream>>>(XW, HS, WP, h0, c0);
  feats_kernel<<<128, 128, 0, stream>>>(HS, Wout, bout, FE);
  viterbi_kernel<<<1, 256, 74048, stream>>>(FE, trans, (float*)d_out);
}